// Round 1
// baseline (2187.842 us; speedup 1.0000x reference)
//
#include <hip/hip_runtime.h>
#include <math.h>

// ---------------------------------------------------------------------------
// MeshGraphUnet2 forward on gfx950.
// Static shapes: N0=50000, E=600000, C=128, DEPTH=3, RATIO=0.5.
// Pipeline per down level: score(f64 dot) -> radix-select top-k -> pool ->
// edge remap -> CSR build -> wave-per-node aggregation -> 3x GEMM(+gelu) -> LN.
// Up level: concat(res, scatter(up)) -> aggregation (reused CSR) -> MLP -> LN.
// ---------------------------------------------------------------------------

__device__ __forceinline__ unsigned int fkey(float f) {
  unsigned int b = __float_as_uint(f);
  return (b & 0x80000000u) ? ~b : (b | 0x80000000u);  // monotonic float->uint
}

__device__ __forceinline__ float gelu_f(float v) {
  return 0.5f * v * (1.0f + erff(v * 0.70710678118654752f));
}

// ---- scoring: key[i] = (float)(x[i,:] . w)  (f64 acc), valt[i] = tanh(dot/||w||)
__global__ void score_kernel(const float* __restrict__ x, const float* __restrict__ w,
                             float* __restrict__ key, float* __restrict__ valt, int n) {
  int wave = threadIdx.x >> 6, lane = threadIdx.x & 63;
  int i = blockIdx.x * 4 + wave;
  if (i >= n) return;
  float2 xv = *(const float2*)&x[(size_t)i * 128 + lane * 2];
  float2 wv = *(const float2*)&w[lane * 2];
  double d  = (double)xv.x * wv.x + (double)xv.y * wv.y;
  double nw = (double)wv.x * wv.x + (double)wv.y * wv.y;
  for (int o = 32; o; o >>= 1) { d += __shfl_down(d, o, 64); nw += __shfl_down(nw, o, 64); }
  if (lane == 0) {
    key[i]  = (float)d;
    valt[i] = (float)tanh(d / sqrt(nw));
  }
}

__global__ void hist_hi_kernel(const float* __restrict__ key, int* __restrict__ hist, int n) {
  int i = blockIdx.x * 256 + threadIdx.x;
  if (i >= n) return;
  atomicAdd(&hist[fkey(key[i]) >> 16], 1);
}

__global__ void hist_lo_kernel(const float* __restrict__ key, const int* __restrict__ meta,
                               int* __restrict__ hist, int n) {
  int i = blockIdx.x * 256 + threadIdx.x;
  if (i >= n) return;
  unsigned u = fkey(key[i]);
  if ((u >> 16) == (unsigned)meta[0]) atomicAdd(&hist[u & 0xFFFFu], 1);
}

// descending scan over 65536 bins; find bin B with cum_before < k <= cum_incl
__global__ void find_hi_kernel(const int* __restrict__ hist, int* __restrict__ meta, int k) {
  __shared__ int part[256];
  int t = threadIdx.x, base = t * 256;
  int s = 0;
  for (int j = 0; j < 256; ++j) s += hist[65535 - (base + j)];
  part[t] = s;
  __syncthreads();
  if (t == 0) { int c = 0; for (int i = 0; i < 256; ++i) { int v = part[i]; part[i] = c; c += v; } }
  __syncthreads();
  int cum = part[t];
  for (int j = 0; j < 256; ++j) {
    int b = 65535 - (base + j);
    int c = hist[b];
    if (cum < k && k <= cum + c) { meta[0] = b; meta[1] = k - cum; }
    cum += c;
  }
}

__global__ void find_lo_kernel(const int* __restrict__ hist, int* __restrict__ meta) {
  __shared__ int part[256];
  int t = threadIdx.x, base = t * 256;
  int m = meta[1], B = meta[0];
  int s = 0;
  for (int j = 0; j < 256; ++j) s += hist[65535 - (base + j)];
  part[t] = s;
  __syncthreads();
  if (t == 0) { int c = 0; for (int i = 0; i < 256; ++i) { int v = part[i]; part[i] = c; c += v; } }
  __syncthreads();
  int cum = part[t];
  for (int j = 0; j < 256; ++j) {
    int b = 65535 - (base + j);
    int c = hist[b];
    if (cum < m && m <= cum + c) {
      meta[3] = (int)((((unsigned)B) << 16) | (unsigned)b);  // threshold key uT
      meta[4] = m - cum;                                     // t_sel ties to take
    }
    cum += c;
  }
  if (t == 0) meta[5] = 0;  // slot counter
}

// single wave: index-ordered list of the first t_sel elements with key == uT
__global__ void tie_kernel(const float* __restrict__ key, const int* __restrict__ meta,
                           int* __restrict__ tiel, int n) {
  unsigned uT = (unsigned)meta[3];
  int tsel = meta[4];
  int lane = threadIdx.x;
  int running = 0;
  for (int base = 0; base < n && running < tsel; base += 64) {
    int i = base + lane;
    bool tie = (i < n) && (fkey(key[i]) == uT);
    unsigned long long mask = __ballot(tie);
    if (tie) {
      int pre = __popcll(mask & ((1ull << lane) - 1ull));
      int pos = running + pre;
      if (pos < tsel && pos < 4096) tiel[pos] = i;
    }
    running += __popcll(mask);
  }
}

__global__ void select_kernel(const float* __restrict__ key, const float* __restrict__ valt,
                              const int* __restrict__ tiel, int* __restrict__ meta,
                              int* __restrict__ perm, float* __restrict__ vals,
                              int* __restrict__ nmap, int n, int k) {
  int i = blockIdx.x * 256 + threadIdx.x;
  if (i > n) return;
  if (i == n) { nmap[n] = k; return; }
  unsigned u  = fkey(key[i]);
  unsigned uT = (unsigned)meta[3];
  bool sel = u > uT;
  if (u == uT) {
    int tsel = meta[4]; if (tsel > 4096) tsel = 4096;
    for (int t = 0; t < tsel; ++t) if (tiel[t] == i) { sel = true; break; }
  }
  if (sel) {
    int slot = atomicAdd(&meta[5], 1);
    perm[slot] = i; vals[slot] = valt[i]; nmap[i] = slot;
  } else {
    nmap[i] = k;
  }
}

__global__ void pool_kernel(const float* __restrict__ x, const int* __restrict__ perm,
                            const float* __restrict__ vals, float* __restrict__ xp, int k) {
  int gid = blockIdx.x * 256 + threadIdx.x;
  int t = gid >> 5;
  if (t >= k) return;
  int c = (gid & 31) << 2;
  float v = vals[t];
  float4 a = *(const float4*)&x[(size_t)perm[t] * 128 + c];
  a.x *= v; a.y *= v; a.z *= v; a.w *= v;
  *(float4*)&xp[(size_t)t * 128 + c] = a;
}

__global__ void remap_kernel(const int* __restrict__ s_in, const int* __restrict__ r_in,
                             const int* __restrict__ nmap, int* __restrict__ s_out,
                             int* __restrict__ r_out, int E, int k) {
  int e = blockIdx.x * 256 + threadIdx.x;
  if (e >= E) return;
  int a = nmap[s_in[e]], b = nmap[r_in[e]];
  if (a == k || b == k) { a = k; b = k; }
  s_out[e] = a; r_out[e] = b;
}

// ---- CSR build (dest-sorted incident lists, both directions) ----
__global__ void deg_kernel(const int* __restrict__ s, const int* __restrict__ r,
                           int* __restrict__ deg, int E, int n) {
  int e = blockIdx.x * 256 + threadIdx.x;
  if (e >= E) return;
  int ss = s[e];
  if (ss >= n) return;  // invalid (dummy) edge
  int rr = r[e];
  atomicAdd(&deg[rr], 1);
  atomicAdd(&deg[ss], 1);
}

// exclusive scan; deg may alias cur
__global__ void scan_kernel(const int* deg, int* off, int* cur, int n) {
  __shared__ int part[1024];
  int t = threadIdx.x;
  int chunk = (n + 1023) / 1024;
  int lo = t * chunk, hi = lo + chunk; if (hi > n) hi = n; if (lo > n) lo = n;
  int s = 0;
  for (int i = lo; i < hi; ++i) s += deg[i];
  part[t] = s;
  __syncthreads();
  if (t == 0) { int c = 0; for (int i = 0; i < 1024; ++i) { int v = part[i]; part[i] = c; c += v; } }
  __syncthreads();
  int c = part[t];
  for (int i = lo; i < hi; ++i) { int d = deg[i]; off[i] = c; cur[i] = c; c += d; }
  if (hi == n) off[n] = c;
}

__global__ void csr_scatter_kernel(const int* __restrict__ s, const int* __restrict__ r,
                                   int* __restrict__ cur, int* __restrict__ idx, int E, int n) {
  int e = blockIdx.x * 256 + threadIdx.x;
  if (e >= E) return;
  int ss = s[e];
  if (ss >= n) return;
  int rr = r[e];
  idx[atomicAdd(&cur[rr], 1)] = ss;
  idx[atomicAdd(&cur[ss], 1)] = rr;
}

// wave-per-node aggregation: agg[v] = sum over incident list of x[src]
template <int C>
__global__ void agg_kernel(const float* __restrict__ x, const int* __restrict__ off,
                           const int* __restrict__ idx, float* __restrict__ agg, int n) {
  int wave = threadIdx.x >> 6, lane = threadIdx.x & 63;
  int v = blockIdx.x * 4 + wave;
  if (v >= n) return;
  int lo = off[v], hi = off[v + 1];
  if (C == 128) {
    int c = lane * 2;
    float ax = 0.f, ay = 0.f;
    for (int j = lo; j < hi; ++j) {
      int u = idx[j];
      float2 a = *(const float2*)&x[(size_t)u * 128 + c];
      ax += a.x; ay += a.y;
    }
    float2 o; o.x = ax; o.y = ay;
    *(float2*)&agg[(size_t)v * 128 + c] = o;
  } else {
    int c = lane * 4;
    float a0 = 0.f, a1 = 0.f, a2 = 0.f, a3 = 0.f;
    for (int j = lo; j < hi; ++j) {
      int u = idx[j];
      float4 a = *(const float4*)&x[(size_t)u * 256 + c];
      a0 += a.x; a1 += a.y; a2 += a.z; a3 += a.w;
    }
    float4 o; o.x = a0; o.y = a1; o.z = a2; o.w = a3;
    *(float4*)&agg[(size_t)v * 256 + c] = o;
  }
}

// ---- f32 GEMM: out[n,128] = act(A[n,CIN] @ W[CIN,128] + bias) ----
template <int CIN, bool GELU>
__global__ __launch_bounds__(256) void gemm_kernel(const float* __restrict__ A,
                                                   const float* __restrict__ W,
                                                   const float* __restrict__ bias,
                                                   float* __restrict__ out, int n) {
  __shared__ float As[64 * 32];
  __shared__ float Ws[32 * 128];
  int t = threadIdx.x;
  int row0 = blockIdx.x * 64;
  int colg = (t & 31) << 2;  // 0..124 step 4
  int rowg = t >> 5;         // 0..7
  float acc[8][4];
#pragma unroll
  for (int i = 0; i < 8; ++i)
#pragma unroll
    for (int j = 0; j < 4; ++j) acc[i][j] = 0.f;

  for (int k0 = 0; k0 < CIN; k0 += 32) {
    __syncthreads();
#pragma unroll
    for (int l = 0; l < 2; ++l) {  // A tile 64x32
      int id = t + l * 256;
      int ar = id >> 3, ac = (id & 7) << 2;
      float4 av = make_float4(0.f, 0.f, 0.f, 0.f);
      if (row0 + ar < n) av = *(const float4*)&A[(size_t)(row0 + ar) * CIN + k0 + ac];
      *(float4*)&As[ar * 32 + ac] = av;
    }
#pragma unroll
    for (int l = 0; l < 4; ++l) {  // W tile 32x128
      int id = t + l * 256;
      int kk = id >> 5, wc = (id & 31) << 2;
      *(float4*)&Ws[kk * 128 + wc] = *(const float4*)&W[(size_t)(k0 + kk) * 128 + wc];
    }
    __syncthreads();
#pragma unroll
    for (int kk = 0; kk < 32; kk += 4) {
      float4 wv[4];
#pragma unroll
      for (int j = 0; j < 4; ++j) wv[j] = *(const float4*)&Ws[(kk + j) * 128 + colg];
#pragma unroll
      for (int i = 0; i < 8; ++i) {
        int rr = rowg + (i << 3);
        float4 av = *(const float4*)&As[rr * 32 + kk];
        acc[i][0] += av.x * wv[0].x + av.y * wv[1].x + av.z * wv[2].x + av.w * wv[3].x;
        acc[i][1] += av.x * wv[0].y + av.y * wv[1].y + av.z * wv[2].y + av.w * wv[3].y;
        acc[i][2] += av.x * wv[0].z + av.y * wv[1].z + av.z * wv[2].z + av.w * wv[3].z;
        acc[i][3] += av.x * wv[0].w + av.y * wv[1].w + av.z * wv[2].w + av.w * wv[3].w;
      }
    }
  }
  float4 bv = *(const float4*)&bias[colg];
#pragma unroll
  for (int i = 0; i < 8; ++i) {
    int rr = row0 + rowg + (i << 3);
    if (rr < n) {
      float4 o = make_float4(acc[i][0] + bv.x, acc[i][1] + bv.y, acc[i][2] + bv.z, acc[i][3] + bv.w);
      if (GELU) { o.x = gelu_f(o.x); o.y = gelu_f(o.y); o.z = gelu_f(o.z); o.w = gelu_f(o.w); }
      *(float4*)&out[(size_t)rr * 128 + colg] = o;
    }
  }
}

__global__ void ln_kernel(const float* __restrict__ h, const float* __restrict__ g,
                          const float* __restrict__ beta, float* __restrict__ out, int n) {
  int wave = threadIdx.x >> 6, lane = threadIdx.x & 63;
  int i = blockIdx.x * 4 + wave;
  if (i >= n) return;
  float2 hv = *(const float2*)&h[(size_t)i * 128 + lane * 2];
  float s = hv.x + hv.y;
  for (int o = 32; o; o >>= 1) s += __shfl_down(s, o, 64);
  float mu = __shfl(s, 0, 64) * (1.0f / 128.0f);
  float dx = hv.x - mu, dy = hv.y - mu;
  float q = dx * dx + dy * dy;
  for (int o = 32; o; o >>= 1) q += __shfl_down(q, o, 64);
  float var = __shfl(q, 0, 64) * (1.0f / 128.0f);
  float rs = rsqrtf(var + 1e-5f);
  float2 gv = *(const float2*)&g[lane * 2];
  float2 bv = *(const float2*)&beta[lane * 2];
  float2 o2; o2.x = gv.x * dx * rs + bv.x; o2.y = gv.y * dy * rs + bv.y;
  *(float2*)&out[(size_t)i * 128 + lane * 2] = o2;
}

// cat[:, :128] = res ; cat[:, 128:] = 0
__global__ void cat_res_kernel(const float* __restrict__ res, float* __restrict__ cat, int n) {
  int gid = blockIdx.x * 256 + threadIdx.x;
  int row = gid >> 6;
  if (row >= n) return;
  int q = gid & 63;
  int c = q << 2;  // q<32 -> [0,128), q>=32 -> [128,256)
  if (q < 32)
    *(float4*)&cat[(size_t)row * 256 + c] = *(const float4*)&res[(size_t)row * 128 + c];
  else {
    float4 z = make_float4(0.f, 0.f, 0.f, 0.f);
    *(float4*)&cat[(size_t)row * 256 + c] = z;
  }
}

// cat[perm[t], 128:] = xdeep[t, :]
__global__ void cat_up_kernel(const float* __restrict__ xd, const int* __restrict__ perm,
                              float* __restrict__ cat, int k) {
  int gid = blockIdx.x * 256 + threadIdx.x;
  int t = gid >> 5;
  if (t >= k) return;
  int c = (gid & 31) << 2;
  *(float4*)&cat[(size_t)perm[t] * 256 + 128 + c] = *(const float4*)&xd[(size_t)t * 128 + c];
}

// ---------------------------------------------------------------------------

static inline int cdiv(int a, int b) { return (a + b - 1) / b; }

extern "C" void kernel_launch(void* const* d_in, const int* in_sizes, int n_in,
                              void* d_out, int out_size, void* d_ws, size_t ws_size,
                              hipStream_t stream) {
  const float* x0   = (const float*)d_in[0];
  const int*   snd  = (const int*)d_in[1];
  const int*   rcv  = (const int*)d_in[2];
  const float* poolw = (const float*)d_in[3];
  const float* dW1 = (const float*)d_in[4];
  const float* db1 = (const float*)d_in[5];
  const float* dW2 = (const float*)d_in[6];
  const float* db2 = (const float*)d_in[7];
  const float* dW3 = (const float*)d_in[8];
  const float* db3 = (const float*)d_in[9];
  const float* dg  = (const float*)d_in[10];
  const float* dbe = (const float*)d_in[11];
  const float* uW1 = (const float*)d_in[12];
  const float* ub1 = (const float*)d_in[13];
  const float* uW2 = (const float*)d_in[14];
  const float* ub2 = (const float*)d_in[15];
  const float* uW3 = (const float*)d_in[16];
  const float* ub3 = (const float*)d_in[17];
  const float* ug  = (const float*)d_in[18];
  const float* ube = (const float*)d_in[19];

  const int N0 = in_sizes[0] / 128;
  const int E  = in_sizes[1];
  const int N1 = (N0 + 1) / 2, N2 = (N1 + 1) / 2, N3 = (N2 + 1) / 2;

  // ---- workspace carve ----
  char* p = (char*)d_ws;
  auto alloc = [&](size_t bytes) -> void* {
    void* r = (void*)p;
    p += (bytes + 255) & ~(size_t)255;
    return r;
  };
  float* key  = (float*)alloc((size_t)N0 * 4);
  float* valt = (float*)alloc((size_t)N0 * 4);
  int*   hist = (int*)alloc(65536 * 4);
  int*   meta = (int*)alloc(64 * 4);
  int*   tiel = (int*)alloc(4096 * 4);
  int*   nmap = (int*)alloc((size_t)(N0 + 1) * 4);
  int*   perm0 = (int*)alloc((size_t)N1 * 4);
  int*   perm1 = (int*)alloc((size_t)N2 * 4);
  int*   perm2 = (int*)alloc((size_t)N3 * 4);
  float* vals  = (float*)alloc((size_t)N1 * 4);
  int *s1 = (int*)alloc((size_t)E * 4), *r1 = (int*)alloc((size_t)E * 4);
  int *s2 = (int*)alloc((size_t)E * 4), *r2 = (int*)alloc((size_t)E * 4);
  int *s3 = (int*)alloc((size_t)E * 4), *r3 = (int*)alloc((size_t)E * 4);
  float* x1 = (float*)alloc((size_t)N1 * 128 * 4);
  float* x2 = (float*)alloc((size_t)N2 * 128 * 4);
  float* x3 = (float*)alloc((size_t)N3 * 128 * 4);
  float* xp = (float*)alloc((size_t)N1 * 128 * 4);
  float* xu2 = (float*)alloc((size_t)N2 * 128 * 4);
  float* xu1 = (float*)alloc((size_t)N1 * 128 * 4);
  float* agg  = (float*)alloc((size_t)N0 * 256 * 4);
  float* hbuf = (float*)alloc((size_t)N0 * 256 * 4);  // cat | h1+h2
  int* off0 = (int*)alloc((size_t)(N0 + 1) * 4); int* cur0 = (int*)alloc((size_t)N0 * 4);
  int* idx0 = (int*)alloc((size_t)2 * E * 4);
  int* off1 = (int*)alloc((size_t)(N1 + 1) * 4); int* cur1 = (int*)alloc((size_t)N1 * 4);
  int* idx1 = (int*)alloc((size_t)2 * E * 4);
  int* off2 = (int*)alloc((size_t)(N2 + 1) * 4); int* cur2 = (int*)alloc((size_t)N2 * 4);
  int* idx2 = (int*)alloc((size_t)2 * E * 4);
  int* off3 = (int*)alloc((size_t)(N3 + 1) * 4); int* cur3 = (int*)alloc((size_t)N3 * 4);
  int* idx3 = (int*)alloc((size_t)2 * E * 4);

  float* h1 = hbuf;
  float* h2 = hbuf + (size_t)N0 * 128;

  // ---- level-0 CSR (for the final up step) ----
  hipMemsetAsync(cur0, 0, (size_t)N0 * 4, stream);
  deg_kernel<<<cdiv(E, 256), 256, 0, stream>>>(snd, rcv, cur0, E, N0);
  scan_kernel<<<1, 1024, 0, stream>>>(cur0, off0, cur0, N0);
  csr_scatter_kernel<<<cdiv(E, 256), 256, 0, stream>>>(snd, rcv, cur0, idx0, E, N0);

  // ---- generic down step ----
  auto down_step = [&](int n, int k, const float* xcur, const int* sin, const int* rin,
                       int* sout, int* rout, int* permL, float* xnext, int lvl,
                       int* offL, int* curL, int* idxL) {
    score_kernel<<<cdiv(n, 4), 256, 0, stream>>>(xcur, poolw + (size_t)lvl * 128, key, valt, n);
    hipMemsetAsync(hist, 0, 65536 * 4, stream);
    hist_hi_kernel<<<cdiv(n, 256), 256, 0, stream>>>(key, hist, n);
    find_hi_kernel<<<1, 256, 0, stream>>>(hist, meta, k);
    hipMemsetAsync(hist, 0, 65536 * 4, stream);
    hist_lo_kernel<<<cdiv(n, 256), 256, 0, stream>>>(key, meta, hist, n);
    find_lo_kernel<<<1, 256, 0, stream>>>(hist, meta);
    tie_kernel<<<1, 64, 0, stream>>>(key, meta, tiel, n);
    select_kernel<<<cdiv(n + 1, 256), 256, 0, stream>>>(key, valt, tiel, meta, permL, vals, nmap, n, k);
    pool_kernel<<<cdiv(k * 32, 256), 256, 0, stream>>>(xcur, permL, vals, xp, k);
    remap_kernel<<<cdiv(E, 256), 256, 0, stream>>>(sin, rin, nmap, sout, rout, E, k);
    hipMemsetAsync(curL, 0, (size_t)k * 4, stream);
    deg_kernel<<<cdiv(E, 256), 256, 0, stream>>>(sout, rout, curL, E, k);
    scan_kernel<<<1, 1024, 0, stream>>>(curL, offL, curL, k);
    csr_scatter_kernel<<<cdiv(E, 256), 256, 0, stream>>>(sout, rout, curL, idxL, E, k);
    agg_kernel<128><<<cdiv(k, 4), 256, 0, stream>>>(xp, offL, idxL, agg, k);
    gemm_kernel<128, true><<<cdiv(k, 64), 256, 0, stream>>>(
        agg, dW1 + (size_t)lvl * 128 * 128, db1 + (size_t)lvl * 128, h1, k);
    gemm_kernel<128, true><<<cdiv(k, 64), 256, 0, stream>>>(
        h1, dW2 + (size_t)lvl * 128 * 128, db2 + (size_t)lvl * 128, h2, k);
    gemm_kernel<128, false><<<cdiv(k, 64), 256, 0, stream>>>(
        h2, dW3 + (size_t)lvl * 128 * 128, db3 + (size_t)lvl * 128, h1, k);
    ln_kernel<<<cdiv(k, 4), 256, 0, stream>>>(h1, dg + (size_t)lvl * 128, dbe + (size_t)lvl * 128,
                                              xnext, k);
  };

  down_step(N0, N1, x0, snd, rcv, s1, r1, perm0, x1, 0, off1, cur1, idx1);
  down_step(N1, N2, x1, s1, r1, s2, r2, perm1, x2, 1, off2, cur2, idx2);
  down_step(N2, N3, x2, s2, r2, s3, r3, perm2, x3, 2, off3, cur3, idx3);

  // ---- generic up step ----
  auto up_step = [&](int n, const float* res, const int* permL, const float* xdeep, int kdeep,
                     int lvl, const int* offL, const int* idxL, float* outbuf) {
    float* cat = hbuf;
    cat_res_kernel<<<cdiv(n * 64, 256), 256, 0, stream>>>(res, cat, n);
    cat_up_kernel<<<cdiv(kdeep * 32, 256), 256, 0, stream>>>(xdeep, permL, cat, kdeep);
    agg_kernel<256><<<cdiv(n, 4), 256, 0, stream>>>(cat, offL, idxL, agg, n);
    gemm_kernel<256, true><<<cdiv(n, 64), 256, 0, stream>>>(
        agg, uW1 + (size_t)lvl * 256 * 128, ub1 + (size_t)lvl * 128, h1, n);  // cat dead now
    gemm_kernel<128, true><<<cdiv(n, 64), 256, 0, stream>>>(
        h1, uW2 + (size_t)lvl * 128 * 128, ub2 + (size_t)lvl * 128, h2, n);
    gemm_kernel<128, false><<<cdiv(n, 64), 256, 0, stream>>>(
        h2, uW3 + (size_t)lvl * 128 * 128, ub3 + (size_t)lvl * 128, agg, n);  // agg dead, reuse
    ln_kernel<<<cdiv(n, 4), 256, 0, stream>>>(agg, ug + (size_t)lvl * 128, ube + (size_t)lvl * 128,
                                              outbuf, n);
  };

  up_step(N2, x2, perm2, x3, N3, 0, off2, idx2, xu2);
  up_step(N1, x1, perm1, xu2, N2, 1, off1, idx1, xu1);
  up_step(N0, x0, perm0, xu1, N1, 2, off0, idx0, (float*)d_out);

  (void)n_in; (void)out_size; (void)ws_size;
}

// Round 2
// 1797.075 us; speedup vs baseline: 1.2174x; 1.2174x over previous
//
#include <hip/hip_runtime.h>
#include <math.h>

// ---------------------------------------------------------------------------
// MeshGraphUnet2 forward on gfx950.  Round 1: parallel top-k selection
// (no single-block serial scans), agg gather unrolled x4 for MLP.
// ---------------------------------------------------------------------------

__device__ __forceinline__ unsigned int fkey(float f) {
  unsigned int b = __float_as_uint(f);
  return (b & 0x80000000u) ? ~b : (b | 0x80000000u);  // monotonic float->uint
}

__device__ __forceinline__ float gelu_f(float v) {
  return 0.5f * v * (1.0f + erff(v * 0.70710678118654752f));
}

// ---- scoring: key[i] = (float)(x[i,:] . w)  (f64 acc), valt[i] = tanh(dot/||w||)
__global__ void score_kernel(const float* __restrict__ x, const float* __restrict__ w,
                             float* __restrict__ key, float* __restrict__ valt, int n) {
  int wave = threadIdx.x >> 6, lane = threadIdx.x & 63;
  int i = blockIdx.x * 4 + wave;
  if (i >= n) return;
  float2 xv = *(const float2*)&x[(size_t)i * 128 + lane * 2];
  float2 wv = *(const float2*)&w[lane * 2];
  double d  = (double)xv.x * wv.x + (double)xv.y * wv.y;
  double nw = (double)wv.x * wv.x + (double)wv.y * wv.y;
  for (int o = 32; o; o >>= 1) { d += __shfl_down(d, o, 64); nw += __shfl_down(nw, o, 64); }
  if (lane == 0) {
    key[i]  = (float)d;
    valt[i] = (float)tanh(d / sqrt(nw));
  }
}

__global__ void hist_hi_kernel(const float* __restrict__ key, int* __restrict__ hist, int n) {
  int i = blockIdx.x * 256 + threadIdx.x;
  if (i >= n) return;
  atomicAdd(&hist[fkey(key[i]) >> 16], 1);
}

__global__ void hist_lo_kernel(const float* __restrict__ key, const int* __restrict__ meta,
                               int* __restrict__ hist, int n) {
  int i = blockIdx.x * 256 + threadIdx.x;
  if (i >= n) return;
  unsigned u = fkey(key[i]);
  if ((u >> 16) == (unsigned)meta[0]) atomicAdd(&hist[u & 0xFFFFu], 1);
}

// 256 blocks x 256 threads: csum[b] = sum of hist[b*256 .. b*256+255]
__global__ void chunk_sum_kernel(const int* __restrict__ hist, int* __restrict__ csum) {
  __shared__ int l[256];
  l[threadIdx.x] = hist[blockIdx.x * 256 + threadIdx.x];
  __syncthreads();
  for (int s = 128; s; s >>= 1) {
    if (threadIdx.x < s) l[threadIdx.x] += l[threadIdx.x + s];
    __syncthreads();
  }
  if (threadIdx.x == 0) csum[blockIdx.x] = l[0];
}

// descending (high bins first) rank-k search using chunk sums; all data via LDS
__global__ void find_hi2_kernel(const int* __restrict__ hist, const int* __restrict__ csum,
                                int* __restrict__ meta, int k) {
  __shared__ int s[256];
  __shared__ int cSh, cumSh;
  int t = threadIdx.x;
  s[t] = csum[t];
  __syncthreads();
  if (t == 0) {
    int cum = 0, c = 0;
    for (int i = 255; i >= 0; --i) {
      if (cum + s[i] >= k) { c = i; break; }
      cum += s[i];
    }
    cSh = c; cumSh = cum;
  }
  __syncthreads();
  int c = cSh;
  s[t] = hist[c * 256 + t];
  __syncthreads();
  if (t == 0) {
    int cum = cumSh;
    for (int b = 255; b >= 0; --b) {
      int v = s[b];
      if (cum + v >= k) { meta[0] = c * 256 + b; meta[1] = k - cum; break; }
      cum += v;
    }
  }
}

__global__ void find_lo2_kernel(const int* __restrict__ hist, const int* __restrict__ csum,
                                int* __restrict__ meta) {
  __shared__ int s[256];
  __shared__ int cSh, cumSh;
  int t = threadIdx.x;
  int m = meta[1], B = meta[0];
  s[t] = csum[t];
  __syncthreads();
  if (t == 0) {
    int cum = 0, c = 0;
    for (int i = 255; i >= 0; --i) {
      if (cum + s[i] >= m) { c = i; break; }
      cum += s[i];
    }
    cSh = c; cumSh = cum;
  }
  __syncthreads();
  int c = cSh;
  s[t] = hist[c * 256 + t];
  __syncthreads();
  if (t == 0) {
    int cum = cumSh;
    for (int b = 255; b >= 0; --b) {
      int v = s[b];
      if (cum + v >= m) {
        meta[3] = (int)((((unsigned)B) << 16) | (unsigned)(c * 256 + b));  // threshold key
        meta[4] = m - cum;                                                 // ties to take
        break;
      }
      cum += v;
    }
    meta[5] = 0;  // slot counter
  }
}

// ---- parallel index-ordered tie ranking ----
__global__ void tie_count_kernel(const float* __restrict__ key, const int* __restrict__ meta,
                                 int* __restrict__ tcnt, int n) {
  __shared__ int cnt[4];
  unsigned uT = (unsigned)meta[3];
  int i = blockIdx.x * 256 + threadIdx.x;
  bool tie = (i < n) && (fkey(key[i]) == uT);
  unsigned long long m = __ballot(tie);
  int lane = threadIdx.x & 63, w = threadIdx.x >> 6;
  if (lane == 0) cnt[w] = __popcll(m);
  __syncthreads();
  if (threadIdx.x == 0) tcnt[blockIdx.x] = cnt[0] + cnt[1] + cnt[2] + cnt[3];
}

__global__ void tie_scan_kernel(const int* __restrict__ tcnt, int* __restrict__ toff, int nb) {
  __shared__ int l[512];
  int t = threadIdx.x;
  for (int b = t; b < nb; b += 256) l[b] = tcnt[b];
  __syncthreads();
  if (t == 0) {
    int c = 0;
    for (int b = 0; b < nb; ++b) { int v = l[b]; l[b] = c; c += v; }
  }
  __syncthreads();
  for (int b = t; b < nb; b += 256) toff[b] = l[b];
}

__global__ void tie_mark_kernel(const float* __restrict__ key, const int* __restrict__ meta,
                                const int* __restrict__ toff, unsigned char* __restrict__ selt,
                                int n) {
  __shared__ int woff[4];
  unsigned uT = (unsigned)meta[3];
  int tsel = meta[4];
  int i = blockIdx.x * 256 + threadIdx.x;
  bool tie = (i < n) && (fkey(key[i]) == uT);
  unsigned long long m = __ballot(tie);
  int lane = threadIdx.x & 63, w = threadIdx.x >> 6;
  if (lane == 0) woff[w] = __popcll(m);
  __syncthreads();
  if (threadIdx.x == 0) {
    int c = 0;
    for (int q = 0; q < 4; ++q) { int v = woff[q]; woff[q] = c; c += v; }
  }
  __syncthreads();
  if (tie) {
    int pre = __popcll(m & ((1ull << lane) - 1ull));
    int rank = toff[blockIdx.x] + woff[w] + pre;
    selt[i] = (rank < tsel) ? 1 : 0;
  }
}

__global__ void select_kernel(const float* __restrict__ key, const float* __restrict__ valt,
                              const unsigned char* __restrict__ selt, int* __restrict__ meta,
                              int* __restrict__ perm, float* __restrict__ vals,
                              int* __restrict__ nmap, int n, int k) {
  int i = blockIdx.x * 256 + threadIdx.x;
  if (i > n) return;
  if (i == n) { nmap[n] = k; return; }
  unsigned u  = fkey(key[i]);
  unsigned uT = (unsigned)meta[3];
  bool sel = (u > uT) || (u == uT && selt[i] != 0);
  if (sel) {
    int slot = atomicAdd(&meta[5], 1);
    perm[slot] = i; vals[slot] = valt[i]; nmap[i] = slot;
  } else {
    nmap[i] = k;
  }
}

__global__ void pool_kernel(const float* __restrict__ x, const int* __restrict__ perm,
                            const float* __restrict__ vals, float* __restrict__ xp, int k) {
  int gid = blockIdx.x * 256 + threadIdx.x;
  int t = gid >> 5;
  if (t >= k) return;
  int c = (gid & 31) << 2;
  float v = vals[t];
  float4 a = *(const float4*)&x[(size_t)perm[t] * 128 + c];
  a.x *= v; a.y *= v; a.z *= v; a.w *= v;
  *(float4*)&xp[(size_t)t * 128 + c] = a;
}

__global__ void remap_kernel(const int* __restrict__ s_in, const int* __restrict__ r_in,
                             const int* __restrict__ nmap, int* __restrict__ s_out,
                             int* __restrict__ r_out, int E, int k) {
  int e = blockIdx.x * 256 + threadIdx.x;
  if (e >= E) return;
  int a = nmap[s_in[e]], b = nmap[r_in[e]];
  if (a == k || b == k) { a = k; b = k; }
  s_out[e] = a; r_out[e] = b;
}

// ---- CSR build (dest-sorted incident lists, both directions) ----
__global__ void deg_kernel(const int* __restrict__ s, const int* __restrict__ r,
                           int* __restrict__ deg, int E, int n) {
  int e = blockIdx.x * 256 + threadIdx.x;
  if (e >= E) return;
  int ss = s[e];
  if (ss >= n) return;  // invalid (dummy) edge
  int rr = r[e];
  atomicAdd(&deg[rr], 1);
  atomicAdd(&deg[ss], 1);
}

// exclusive scan; deg may alias cur
__global__ void scan_kernel(const int* deg, int* off, int* cur, int n) {
  __shared__ int part[1024];
  int t = threadIdx.x;
  int chunk = (n + 1023) / 1024;
  int lo = t * chunk, hi = lo + chunk; if (hi > n) hi = n; if (lo > n) lo = n;
  int s = 0;
  for (int i = lo; i < hi; ++i) s += deg[i];
  part[t] = s;
  __syncthreads();
  if (t == 0) { int c = 0; for (int i = 0; i < 1024; ++i) { int v = part[i]; part[i] = c; c += v; } }
  __syncthreads();
  int c = part[t];
  for (int i = lo; i < hi; ++i) { int d = deg[i]; off[i] = c; cur[i] = c; c += d; }
  if (hi == n) off[n] = c;
}

__global__ void csr_scatter_kernel(const int* __restrict__ s, const int* __restrict__ r,
                                   int* __restrict__ cur, int* __restrict__ idx, int E, int n) {
  int e = blockIdx.x * 256 + threadIdx.x;
  if (e >= E) return;
  int ss = s[e];
  if (ss >= n) return;
  int rr = r[e];
  idx[atomicAdd(&cur[rr], 1)] = ss;
  idx[atomicAdd(&cur[ss], 1)] = rr;
}

// wave-per-node aggregation: agg[v] = sum over incident list of x[src]; x4 unroll for MLP
template <int C>
__global__ void agg_kernel(const float* __restrict__ x, const int* __restrict__ off,
                           const int* __restrict__ idx, float* __restrict__ agg, int n) {
  int wave = threadIdx.x >> 6, lane = threadIdx.x & 63;
  int v = blockIdx.x * 4 + wave;
  if (v >= n) return;
  int lo = off[v], hi = off[v + 1];
  if (C == 128) {
    int c = lane * 2;
    float ax = 0.f, ay = 0.f;
    int j = lo;
    for (; j + 4 <= hi; j += 4) {
      int u0 = idx[j], u1 = idx[j + 1], u2 = idx[j + 2], u3 = idx[j + 3];
      float2 a0 = *(const float2*)&x[(size_t)u0 * 128 + c];
      float2 a1 = *(const float2*)&x[(size_t)u1 * 128 + c];
      float2 a2 = *(const float2*)&x[(size_t)u2 * 128 + c];
      float2 a3 = *(const float2*)&x[(size_t)u3 * 128 + c];
      ax += a0.x + a1.x + a2.x + a3.x;
      ay += a0.y + a1.y + a2.y + a3.y;
    }
    for (; j < hi; ++j) {
      int u = idx[j];
      float2 a = *(const float2*)&x[(size_t)u * 128 + c];
      ax += a.x; ay += a.y;
    }
    float2 o; o.x = ax; o.y = ay;
    *(float2*)&agg[(size_t)v * 128 + c] = o;
  } else {
    int c = lane * 4;
    float a0 = 0.f, a1 = 0.f, a2 = 0.f, a3 = 0.f;
    int j = lo;
    for (; j + 4 <= hi; j += 4) {
      int u0 = idx[j], u1 = idx[j + 1], u2 = idx[j + 2], u3 = idx[j + 3];
      float4 b0 = *(const float4*)&x[(size_t)u0 * 256 + c];
      float4 b1 = *(const float4*)&x[(size_t)u1 * 256 + c];
      float4 b2 = *(const float4*)&x[(size_t)u2 * 256 + c];
      float4 b3 = *(const float4*)&x[(size_t)u3 * 256 + c];
      a0 += b0.x + b1.x + b2.x + b3.x;
      a1 += b0.y + b1.y + b2.y + b3.y;
      a2 += b0.z + b1.z + b2.z + b3.z;
      a3 += b0.w + b1.w + b2.w + b3.w;
    }
    for (; j < hi; ++j) {
      int u = idx[j];
      float4 b = *(const float4*)&x[(size_t)u * 256 + c];
      a0 += b.x; a1 += b.y; a2 += b.z; a3 += b.w;
    }
    float4 o; o.x = a0; o.y = a1; o.z = a2; o.w = a3;
    *(float4*)&agg[(size_t)v * 256 + c] = o;
  }
}

// ---- f32 GEMM: out[n,128] = act(A[n,CIN] @ W[CIN,128] + bias) ----
template <int CIN, bool GELU>
__global__ __launch_bounds__(256) void gemm_kernel(const float* __restrict__ A,
                                                   const float* __restrict__ W,
                                                   const float* __restrict__ bias,
                                                   float* __restrict__ out, int n) {
  __shared__ float As[64 * 32];
  __shared__ float Ws[32 * 128];
  int t = threadIdx.x;
  int row0 = blockIdx.x * 64;
  int colg = (t & 31) << 2;  // 0..124 step 4
  int rowg = t >> 5;         // 0..7
  float acc[8][4];
#pragma unroll
  for (int i = 0; i < 8; ++i)
#pragma unroll
    for (int j = 0; j < 4; ++j) acc[i][j] = 0.f;

  for (int k0 = 0; k0 < CIN; k0 += 32) {
    __syncthreads();
#pragma unroll
    for (int l = 0; l < 2; ++l) {  // A tile 64x32
      int id = t + l * 256;
      int ar = id >> 3, ac = (id & 7) << 2;
      float4 av = make_float4(0.f, 0.f, 0.f, 0.f);
      if (row0 + ar < n) av = *(const float4*)&A[(size_t)(row0 + ar) * CIN + k0 + ac];
      *(float4*)&As[ar * 32 + ac] = av;
    }
#pragma unroll
    for (int l = 0; l < 4; ++l) {  // W tile 32x128
      int id = t + l * 256;
      int kk = id >> 5, wc = (id & 31) << 2;
      *(float4*)&Ws[kk * 128 + wc] = *(const float4*)&W[(size_t)(k0 + kk) * 128 + wc];
    }
    __syncthreads();
#pragma unroll
    for (int kk = 0; kk < 32; kk += 4) {
      float4 wv[4];
#pragma unroll
      for (int j = 0; j < 4; ++j) wv[j] = *(const float4*)&Ws[(kk + j) * 128 + colg];
#pragma unroll
      for (int i = 0; i < 8; ++i) {
        int rr = rowg + (i << 3);
        float4 av = *(const float4*)&As[rr * 32 + kk];
        acc[i][0] += av.x * wv[0].x + av.y * wv[1].x + av.z * wv[2].x + av.w * wv[3].x;
        acc[i][1] += av.x * wv[0].y + av.y * wv[1].y + av.z * wv[2].y + av.w * wv[3].y;
        acc[i][2] += av.x * wv[0].z + av.y * wv[1].z + av.z * wv[2].z + av.w * wv[3].z;
        acc[i][3] += av.x * wv[0].w + av.y * wv[1].w + av.z * wv[2].w + av.w * wv[3].w;
      }
    }
  }
  float4 bv = *(const float4*)&bias[colg];
#pragma unroll
  for (int i = 0; i < 8; ++i) {
    int rr = row0 + rowg + (i << 3);
    if (rr < n) {
      float4 o = make_float4(acc[i][0] + bv.x, acc[i][1] + bv.y, acc[i][2] + bv.z, acc[i][3] + bv.w);
      if (GELU) { o.x = gelu_f(o.x); o.y = gelu_f(o.y); o.z = gelu_f(o.z); o.w = gelu_f(o.w); }
      *(float4*)&out[(size_t)rr * 128 + colg] = o;
    }
  }
}

__global__ void ln_kernel(const float* __restrict__ h, const float* __restrict__ g,
                          const float* __restrict__ beta, float* __restrict__ out, int n) {
  int wave = threadIdx.x >> 6, lane = threadIdx.x & 63;
  int i = blockIdx.x * 4 + wave;
  if (i >= n) return;
  float2 hv = *(const float2*)&h[(size_t)i * 128 + lane * 2];
  float s = hv.x + hv.y;
  for (int o = 32; o; o >>= 1) s += __shfl_down(s, o, 64);
  float mu = __shfl(s, 0, 64) * (1.0f / 128.0f);
  float dx = hv.x - mu, dy = hv.y - mu;
  float q = dx * dx + dy * dy;
  for (int o = 32; o; o >>= 1) q += __shfl_down(q, o, 64);
  float var = __shfl(q, 0, 64) * (1.0f / 128.0f);
  float rs = rsqrtf(var + 1e-5f);
  float2 gv = *(const float2*)&g[lane * 2];
  float2 bv = *(const float2*)&beta[lane * 2];
  float2 o2; o2.x = gv.x * dx * rs + bv.x; o2.y = gv.y * dy * rs + bv.y;
  *(float2*)&out[(size_t)i * 128 + lane * 2] = o2;
}

// cat[:, :128] = res ; cat[:, 128:] = 0
__global__ void cat_res_kernel(const float* __restrict__ res, float* __restrict__ cat, int n) {
  int gid = blockIdx.x * 256 + threadIdx.x;
  int row = gid >> 6;
  if (row >= n) return;
  int q = gid & 63;
  int c = q << 2;  // q<32 -> [0,128), q>=32 -> [128,256)
  if (q < 32)
    *(float4*)&cat[(size_t)row * 256 + c] = *(const float4*)&res[(size_t)row * 128 + c];
  else {
    float4 z = make_float4(0.f, 0.f, 0.f, 0.f);
    *(float4*)&cat[(size_t)row * 256 + c] = z;
  }
}

// cat[perm[t], 128:] = xdeep[t, :]
__global__ void cat_up_kernel(const float* __restrict__ xd, const int* __restrict__ perm,
                              float* __restrict__ cat, int k) {
  int gid = blockIdx.x * 256 + threadIdx.x;
  int t = gid >> 5;
  if (t >= k) return;
  int c = (gid & 31) << 2;
  *(float4*)&cat[(size_t)perm[t] * 256 + 128 + c] = *(const float4*)&xd[(size_t)t * 128 + c];
}

// ---------------------------------------------------------------------------

static inline int cdiv(int a, int b) { return (a + b - 1) / b; }

extern "C" void kernel_launch(void* const* d_in, const int* in_sizes, int n_in,
                              void* d_out, int out_size, void* d_ws, size_t ws_size,
                              hipStream_t stream) {
  const float* x0   = (const float*)d_in[0];
  const int*   snd  = (const int*)d_in[1];
  const int*   rcv  = (const int*)d_in[2];
  const float* poolw = (const float*)d_in[3];
  const float* dW1 = (const float*)d_in[4];
  const float* db1 = (const float*)d_in[5];
  const float* dW2 = (const float*)d_in[6];
  const float* db2 = (const float*)d_in[7];
  const float* dW3 = (const float*)d_in[8];
  const float* db3 = (const float*)d_in[9];
  const float* dg  = (const float*)d_in[10];
  const float* dbe = (const float*)d_in[11];
  const float* uW1 = (const float*)d_in[12];
  const float* ub1 = (const float*)d_in[13];
  const float* uW2 = (const float*)d_in[14];
  const float* ub2 = (const float*)d_in[15];
  const float* uW3 = (const float*)d_in[16];
  const float* ub3 = (const float*)d_in[17];
  const float* ug  = (const float*)d_in[18];
  const float* ube = (const float*)d_in[19];

  const int N0 = in_sizes[0] / 128;
  const int E  = in_sizes[1];
  const int N1 = (N0 + 1) / 2, N2 = (N1 + 1) / 2, N3 = (N2 + 1) / 2;

  // ---- workspace carve ----
  char* p = (char*)d_ws;
  auto alloc = [&](size_t bytes) -> void* {
    void* r = (void*)p;
    p += (bytes + 255) & ~(size_t)255;
    return r;
  };
  float* key  = (float*)alloc((size_t)N0 * 4);
  float* valt = (float*)alloc((size_t)N0 * 4);
  int*   hist = (int*)alloc(65536 * 4);
  int*   csum = (int*)alloc(256 * 4);
  int*   meta = (int*)alloc(64 * 4);
  int*   tcnt = (int*)alloc(512 * 4);
  int*   toff = (int*)alloc(512 * 4);
  unsigned char* selt = (unsigned char*)alloc((size_t)N0);
  int*   nmap = (int*)alloc((size_t)(N0 + 1) * 4);
  int*   perm0 = (int*)alloc((size_t)N1 * 4);
  int*   perm1 = (int*)alloc((size_t)N2 * 4);
  int*   perm2 = (int*)alloc((size_t)N3 * 4);
  float* vals  = (float*)alloc((size_t)N1 * 4);
  int *s1 = (int*)alloc((size_t)E * 4), *r1 = (int*)alloc((size_t)E * 4);
  int *s2 = (int*)alloc((size_t)E * 4), *r2 = (int*)alloc((size_t)E * 4);
  int *s3 = (int*)alloc((size_t)E * 4), *r3 = (int*)alloc((size_t)E * 4);
  float* x1 = (float*)alloc((size_t)N1 * 128 * 4);
  float* x2 = (float*)alloc((size_t)N2 * 128 * 4);
  float* x3 = (float*)alloc((size_t)N3 * 128 * 4);
  float* xp = (float*)alloc((size_t)N1 * 128 * 4);
  float* xu2 = (float*)alloc((size_t)N2 * 128 * 4);
  float* xu1 = (float*)alloc((size_t)N1 * 128 * 4);
  float* agg  = (float*)alloc((size_t)N0 * 256 * 4);
  float* hbuf = (float*)alloc((size_t)N0 * 256 * 4);  // cat | h1+h2
  int* off0 = (int*)alloc((size_t)(N0 + 1) * 4); int* cur0 = (int*)alloc((size_t)N0 * 4);
  int* idx0 = (int*)alloc((size_t)2 * E * 4);
  int* off1 = (int*)alloc((size_t)(N1 + 1) * 4); int* cur1 = (int*)alloc((size_t)N1 * 4);
  int* idx1 = (int*)alloc((size_t)2 * E * 4);
  int* off2 = (int*)alloc((size_t)(N2 + 1) * 4); int* cur2 = (int*)alloc((size_t)N2 * 4);
  int* idx2 = (int*)alloc((size_t)2 * E * 4);
  int* off3 = (int*)alloc((size_t)(N3 + 1) * 4); int* cur3 = (int*)alloc((size_t)N3 * 4);
  int* idx3 = (int*)alloc((size_t)2 * E * 4);

  float* h1 = hbuf;
  float* h2 = hbuf + (size_t)N0 * 128;

  // ---- level-0 CSR (for the final up step) ----
  hipMemsetAsync(cur0, 0, (size_t)N0 * 4, stream);
  deg_kernel<<<cdiv(E, 256), 256, 0, stream>>>(snd, rcv, cur0, E, N0);
  scan_kernel<<<1, 1024, 0, stream>>>(cur0, off0, cur0, N0);
  csr_scatter_kernel<<<cdiv(E, 256), 256, 0, stream>>>(snd, rcv, cur0, idx0, E, N0);

  // ---- generic down step ----
  auto down_step = [&](int n, int k, const float* xcur, const int* sin, const int* rin,
                       int* sout, int* rout, int* permL, float* xnext, int lvl,
                       int* offL, int* curL, int* idxL) {
    int nb = cdiv(n, 256);
    score_kernel<<<cdiv(n, 4), 256, 0, stream>>>(xcur, poolw + (size_t)lvl * 128, key, valt, n);
    hipMemsetAsync(hist, 0, 65536 * 4, stream);
    hist_hi_kernel<<<nb, 256, 0, stream>>>(key, hist, n);
    chunk_sum_kernel<<<256, 256, 0, stream>>>(hist, csum);
    find_hi2_kernel<<<1, 256, 0, stream>>>(hist, csum, meta, k);
    hipMemsetAsync(hist, 0, 65536 * 4, stream);
    hist_lo_kernel<<<nb, 256, 0, stream>>>(key, meta, hist, n);
    chunk_sum_kernel<<<256, 256, 0, stream>>>(hist, csum);
    find_lo2_kernel<<<1, 256, 0, stream>>>(hist, csum, meta);
    tie_count_kernel<<<nb, 256, 0, stream>>>(key, meta, tcnt, n);
    tie_scan_kernel<<<1, 256, 0, stream>>>(tcnt, toff, nb);
    tie_mark_kernel<<<nb, 256, 0, stream>>>(key, meta, toff, selt, n);
    select_kernel<<<cdiv(n + 1, 256), 256, 0, stream>>>(key, valt, selt, meta, permL, vals, nmap, n, k);
    pool_kernel<<<cdiv(k * 32, 256), 256, 0, stream>>>(xcur, permL, vals, xp, k);
    remap_kernel<<<cdiv(E, 256), 256, 0, stream>>>(sin, rin, nmap, sout, rout, E, k);
    hipMemsetAsync(curL, 0, (size_t)k * 4, stream);
    deg_kernel<<<cdiv(E, 256), 256, 0, stream>>>(sout, rout, curL, E, k);
    scan_kernel<<<1, 1024, 0, stream>>>(curL, offL, curL, k);
    csr_scatter_kernel<<<cdiv(E, 256), 256, 0, stream>>>(sout, rout, curL, idxL, E, k);
    agg_kernel<128><<<cdiv(k, 4), 256, 0, stream>>>(xp, offL, idxL, agg, k);
    gemm_kernel<128, true><<<cdiv(k, 64), 256, 0, stream>>>(
        agg, dW1 + (size_t)lvl * 128 * 128, db1 + (size_t)lvl * 128, h1, k);
    gemm_kernel<128, true><<<cdiv(k, 64), 256, 0, stream>>>(
        h1, dW2 + (size_t)lvl * 128 * 128, db2 + (size_t)lvl * 128, h2, k);
    gemm_kernel<128, false><<<cdiv(k, 64), 256, 0, stream>>>(
        h2, dW3 + (size_t)lvl * 128 * 128, db3 + (size_t)lvl * 128, h1, k);
    ln_kernel<<<cdiv(k, 4), 256, 0, stream>>>(h1, dg + (size_t)lvl * 128, dbe + (size_t)lvl * 128,
                                              xnext, k);
  };

  down_step(N0, N1, x0, snd, rcv, s1, r1, perm0, x1, 0, off1, cur1, idx1);
  down_step(N1, N2, x1, s1, r1, s2, r2, perm1, x2, 1, off2, cur2, idx2);
  down_step(N2, N3, x2, s2, r2, s3, r3, perm2, x3, 2, off3, cur3, idx3);

  // ---- generic up step ----
  auto up_step = [&](int n, const float* res, const int* permL, const float* xdeep, int kdeep,
                     int lvl, const int* offL, const int* idxL, float* outbuf) {
    float* cat = hbuf;
    cat_res_kernel<<<cdiv(n * 64, 256), 256, 0, stream>>>(res, cat, n);
    cat_up_kernel<<<cdiv(kdeep * 32, 256), 256, 0, stream>>>(xdeep, permL, cat, kdeep);
    agg_kernel<256><<<cdiv(n, 4), 256, 0, stream>>>(cat, offL, idxL, agg, n);
    gemm_kernel<256, true><<<cdiv(n, 64), 256, 0, stream>>>(
        agg, uW1 + (size_t)lvl * 256 * 128, ub1 + (size_t)lvl * 128, h1, n);  // cat dead now
    gemm_kernel<128, true><<<cdiv(n, 64), 256, 0, stream>>>(
        h1, uW2 + (size_t)lvl * 128 * 128, ub2 + (size_t)lvl * 128, h2, n);
    gemm_kernel<128, false><<<cdiv(n, 64), 256, 0, stream>>>(
        h2, uW3 + (size_t)lvl * 128 * 128, ub3 + (size_t)lvl * 128, agg, n);  // agg dead, reuse
    ln_kernel<<<cdiv(n, 4), 256, 0, stream>>>(agg, ug + (size_t)lvl * 128, ube + (size_t)lvl * 128,
                                              outbuf, n);
  };

  up_step(N2, x2, perm2, x3, N3, 0, off2, idx2, xu2);
  up_step(N1, x1, perm1, xu2, N2, 1, off1, idx1, xu1);
  up_step(N0, x0, perm0, xu1, N1, 2, off0, idx0, (float*)d_out);

  (void)n_in; (void)out_size; (void)ws_size;
}

// Round 3
// 1388.362 us; speedup vs baseline: 1.5758x; 1.2944x over previous
//
#include <hip/hip_runtime.h>
#include <math.h>

// ---------------------------------------------------------------------------
// MeshGraphUnet2 forward on gfx950.  Round 2: up path in bf16 (cat, agg,
// MFMA MLPs with f32 accumulation). Down path stays f32 (feeds top-k).
// ---------------------------------------------------------------------------

typedef unsigned short u16;
typedef short bf16x8 __attribute__((ext_vector_type(8)));
typedef float f32x4 __attribute__((ext_vector_type(4)));

__device__ __forceinline__ unsigned int fkey(float f) {
  unsigned int b = __float_as_uint(f);
  return (b & 0x80000000u) ? ~b : (b | 0x80000000u);  // monotonic float->uint
}

__device__ __forceinline__ float gelu_f(float v) {
  return 0.5f * v * (1.0f + erff(v * 0.70710678118654752f));
}

__device__ __forceinline__ u16 f2bf(float f) {
  unsigned u = __float_as_uint(f);
  u = (u + 0x7FFFu + ((u >> 16) & 1u)) >> 16;  // round-nearest-even
  return (u16)u;
}
__device__ __forceinline__ float bf2f(u16 u) {
  return __uint_as_float(((unsigned)u) << 16);
}

// ---- scoring: key[i] = (float)(x[i,:] . w)  (f64 acc), valt[i] = tanh(dot/||w||)
__global__ void score_kernel(const float* __restrict__ x, const float* __restrict__ w,
                             float* __restrict__ key, float* __restrict__ valt, int n) {
  int wave = threadIdx.x >> 6, lane = threadIdx.x & 63;
  int i = blockIdx.x * 4 + wave;
  if (i >= n) return;
  float2 xv = *(const float2*)&x[(size_t)i * 128 + lane * 2];
  float2 wv = *(const float2*)&w[lane * 2];
  double d  = (double)xv.x * wv.x + (double)xv.y * wv.y;
  double nw = (double)wv.x * wv.x + (double)wv.y * wv.y;
  for (int o = 32; o; o >>= 1) { d += __shfl_down(d, o, 64); nw += __shfl_down(nw, o, 64); }
  if (lane == 0) {
    key[i]  = (float)d;
    valt[i] = (float)tanh(d / sqrt(nw));
  }
}

__global__ void hist_hi_kernel(const float* __restrict__ key, int* __restrict__ hist, int n) {
  int i = blockIdx.x * 256 + threadIdx.x;
  if (i >= n) return;
  atomicAdd(&hist[fkey(key[i]) >> 16], 1);
}

__global__ void hist_lo_kernel(const float* __restrict__ key, const int* __restrict__ meta,
                               int* __restrict__ hist, int n) {
  int i = blockIdx.x * 256 + threadIdx.x;
  if (i >= n) return;
  unsigned u = fkey(key[i]);
  if ((u >> 16) == (unsigned)meta[0]) atomicAdd(&hist[u & 0xFFFFu], 1);
}

__global__ void chunk_sum_kernel(const int* __restrict__ hist, int* __restrict__ csum) {
  __shared__ int l[256];
  l[threadIdx.x] = hist[blockIdx.x * 256 + threadIdx.x];
  __syncthreads();
  for (int s = 128; s; s >>= 1) {
    if (threadIdx.x < s) l[threadIdx.x] += l[threadIdx.x + s];
    __syncthreads();
  }
  if (threadIdx.x == 0) csum[blockIdx.x] = l[0];
}

__global__ void find_hi2_kernel(const int* __restrict__ hist, const int* __restrict__ csum,
                                int* __restrict__ meta, int k) {
  __shared__ int s[256];
  __shared__ int cSh, cumSh;
  int t = threadIdx.x;
  s[t] = csum[t];
  __syncthreads();
  if (t == 0) {
    int cum = 0, c = 0;
    for (int i = 255; i >= 0; --i) {
      if (cum + s[i] >= k) { c = i; break; }
      cum += s[i];
    }
    cSh = c; cumSh = cum;
  }
  __syncthreads();
  int c = cSh;
  s[t] = hist[c * 256 + t];
  __syncthreads();
  if (t == 0) {
    int cum = cumSh;
    for (int b = 255; b >= 0; --b) {
      int v = s[b];
      if (cum + v >= k) { meta[0] = c * 256 + b; meta[1] = k - cum; break; }
      cum += v;
    }
  }
}

__global__ void find_lo2_kernel(const int* __restrict__ hist, const int* __restrict__ csum,
                                int* __restrict__ meta) {
  __shared__ int s[256];
  __shared__ int cSh, cumSh;
  int t = threadIdx.x;
  int m = meta[1], B = meta[0];
  s[t] = csum[t];
  __syncthreads();
  if (t == 0) {
    int cum = 0, c = 0;
    for (int i = 255; i >= 0; --i) {
      if (cum + s[i] >= m) { c = i; break; }
      cum += s[i];
    }
    cSh = c; cumSh = cum;
  }
  __syncthreads();
  int c = cSh;
  s[t] = hist[c * 256 + t];
  __syncthreads();
  if (t == 0) {
    int cum = cumSh;
    for (int b = 255; b >= 0; --b) {
      int v = s[b];
      if (cum + v >= m) {
        meta[3] = (int)((((unsigned)B) << 16) | (unsigned)(c * 256 + b));
        meta[4] = m - cum;
        break;
      }
      cum += v;
    }
    meta[5] = 0;
  }
}

__global__ void tie_count_kernel(const float* __restrict__ key, const int* __restrict__ meta,
                                 int* __restrict__ tcnt, int n) {
  __shared__ int cnt[4];
  unsigned uT = (unsigned)meta[3];
  int i = blockIdx.x * 256 + threadIdx.x;
  bool tie = (i < n) && (fkey(key[i]) == uT);
  unsigned long long m = __ballot(tie);
  int lane = threadIdx.x & 63, w = threadIdx.x >> 6;
  if (lane == 0) cnt[w] = __popcll(m);
  __syncthreads();
  if (threadIdx.x == 0) tcnt[blockIdx.x] = cnt[0] + cnt[1] + cnt[2] + cnt[3];
}

__global__ void tie_scan_kernel(const int* __restrict__ tcnt, int* __restrict__ toff, int nb) {
  __shared__ int l[512];
  int t = threadIdx.x;
  for (int b = t; b < nb; b += 256) l[b] = tcnt[b];
  __syncthreads();
  if (t == 0) {
    int c = 0;
    for (int b = 0; b < nb; ++b) { int v = l[b]; l[b] = c; c += v; }
  }
  __syncthreads();
  for (int b = t; b < nb; b += 256) toff[b] = l[b];
}

__global__ void tie_mark_kernel(const float* __restrict__ key, const int* __restrict__ meta,
                                const int* __restrict__ toff, unsigned char* __restrict__ selt,
                                int n) {
  __shared__ int woff[4];
  unsigned uT = (unsigned)meta[3];
  int tsel = meta[4];
  int i = blockIdx.x * 256 + threadIdx.x;
  bool tie = (i < n) && (fkey(key[i]) == uT);
  unsigned long long m = __ballot(tie);
  int lane = threadIdx.x & 63, w = threadIdx.x >> 6;
  if (lane == 0) woff[w] = __popcll(m);
  __syncthreads();
  if (threadIdx.x == 0) {
    int c = 0;
    for (int q = 0; q < 4; ++q) { int v = woff[q]; woff[q] = c; c += v; }
  }
  __syncthreads();
  if (tie) {
    int pre = __popcll(m & ((1ull << lane) - 1ull));
    int rank = toff[blockIdx.x] + woff[w] + pre;
    selt[i] = (rank < tsel) ? 1 : 0;
  }
}

__global__ void select_kernel(const float* __restrict__ key, const float* __restrict__ valt,
                              const unsigned char* __restrict__ selt, int* __restrict__ meta,
                              int* __restrict__ perm, float* __restrict__ vals,
                              int* __restrict__ nmap, int n, int k) {
  int i = blockIdx.x * 256 + threadIdx.x;
  if (i > n) return;
  if (i == n) { nmap[n] = k; return; }
  unsigned u  = fkey(key[i]);
  unsigned uT = (unsigned)meta[3];
  bool sel = (u > uT) || (u == uT && selt[i] != 0);
  if (sel) {
    int slot = atomicAdd(&meta[5], 1);
    perm[slot] = i; vals[slot] = valt[i]; nmap[i] = slot;
  } else {
    nmap[i] = k;
  }
}

__global__ void pool_kernel(const float* __restrict__ x, const int* __restrict__ perm,
                            const float* __restrict__ vals, float* __restrict__ xp, int k) {
  int gid = blockIdx.x * 256 + threadIdx.x;
  int t = gid >> 5;
  if (t >= k) return;
  int c = (gid & 31) << 2;
  float v = vals[t];
  float4 a = *(const float4*)&x[(size_t)perm[t] * 128 + c];
  a.x *= v; a.y *= v; a.z *= v; a.w *= v;
  *(float4*)&xp[(size_t)t * 128 + c] = a;
}

__global__ void remap_kernel(const int* __restrict__ s_in, const int* __restrict__ r_in,
                             const int* __restrict__ nmap, int* __restrict__ s_out,
                             int* __restrict__ r_out, int E, int k) {
  int e = blockIdx.x * 256 + threadIdx.x;
  if (e >= E) return;
  int a = nmap[s_in[e]], b = nmap[r_in[e]];
  if (a == k || b == k) { a = k; b = k; }
  s_out[e] = a; r_out[e] = b;
}

// ---- CSR build ----
__global__ void deg_kernel(const int* __restrict__ s, const int* __restrict__ r,
                           int* __restrict__ deg, int E, int n) {
  int e = blockIdx.x * 256 + threadIdx.x;
  if (e >= E) return;
  int ss = s[e];
  if (ss >= n) return;
  int rr = r[e];
  atomicAdd(&deg[rr], 1);
  atomicAdd(&deg[ss], 1);
}

__global__ void scan_kernel(const int* deg, int* off, int* cur, int n) {
  __shared__ int part[1024];
  int t = threadIdx.x;
  int chunk = (n + 1023) / 1024;
  int lo = t * chunk, hi = lo + chunk; if (hi > n) hi = n; if (lo > n) lo = n;
  int s = 0;
  for (int i = lo; i < hi; ++i) s += deg[i];
  part[t] = s;
  __syncthreads();
  if (t == 0) { int c = 0; for (int i = 0; i < 1024; ++i) { int v = part[i]; part[i] = c; c += v; } }
  __syncthreads();
  int c = part[t];
  for (int i = lo; i < hi; ++i) { int d = deg[i]; off[i] = c; cur[i] = c; c += d; }
  if (hi == n) off[n] = c;
}

__global__ void csr_scatter_kernel(const int* __restrict__ s, const int* __restrict__ r,
                                   int* __restrict__ cur, int* __restrict__ idx, int E, int n) {
  int e = blockIdx.x * 256 + threadIdx.x;
  if (e >= E) return;
  int ss = s[e];
  if (ss >= n) return;
  int rr = r[e];
  idx[atomicAdd(&cur[rr], 1)] = ss;
  idx[atomicAdd(&cur[ss], 1)] = rr;
}

// ---- down-path f32 aggregation (C=128) ----
__global__ void agg_kernel(const float* __restrict__ x, const int* __restrict__ off,
                           const int* __restrict__ idx, float* __restrict__ agg, int n) {
  int wave = threadIdx.x >> 6, lane = threadIdx.x & 63;
  int v = blockIdx.x * 4 + wave;
  if (v >= n) return;
  int lo = off[v], hi = off[v + 1];
  int c = lane * 2;
  float ax = 0.f, ay = 0.f;
  int j = lo;
  for (; j + 4 <= hi; j += 4) {
    int u0 = idx[j], u1 = idx[j + 1], u2 = idx[j + 2], u3 = idx[j + 3];
    float2 a0 = *(const float2*)&x[(size_t)u0 * 128 + c];
    float2 a1 = *(const float2*)&x[(size_t)u1 * 128 + c];
    float2 a2 = *(const float2*)&x[(size_t)u2 * 128 + c];
    float2 a3 = *(const float2*)&x[(size_t)u3 * 128 + c];
    ax += a0.x + a1.x + a2.x + a3.x;
    ay += a0.y + a1.y + a2.y + a3.y;
  }
  for (; j < hi; ++j) {
    int u = idx[j];
    float2 a = *(const float2*)&x[(size_t)u * 128 + c];
    ax += a.x; ay += a.y;
  }
  float2 o; o.x = ax; o.y = ay;
  *(float2*)&agg[(size_t)v * 128 + c] = o;
}

// ---- up-path bf16 aggregation (C=256 bf16 in, bf16 out, f32 accum) ----
__global__ void agg_bf_kernel(const u16* __restrict__ x, const int* __restrict__ off,
                              const int* __restrict__ idx, u16* __restrict__ agg, int n) {
  int wave = threadIdx.x >> 6, lane = threadIdx.x & 63;
  int v = blockIdx.x * 4 + wave;
  if (v >= n) return;
  int lo = off[v], hi = off[v + 1];
  int c = lane * 4;
  float a0 = 0.f, a1 = 0.f, a2 = 0.f, a3 = 0.f;
  int j = lo;
  for (; j + 8 <= hi; j += 8) {
    int us[8];
#pragma unroll
    for (int q = 0; q < 8; ++q) us[q] = idx[j + q];
#pragma unroll
    for (int q = 0; q < 8; ++q) {
      ushort4 b = *(const ushort4*)&x[(size_t)us[q] * 256 + c];
      a0 += bf2f(b.x); a1 += bf2f(b.y); a2 += bf2f(b.z); a3 += bf2f(b.w);
    }
  }
  for (; j < hi; ++j) {
    ushort4 b = *(const ushort4*)&x[(size_t)idx[j] * 256 + c];
    a0 += bf2f(b.x); a1 += bf2f(b.y); a2 += bf2f(b.z); a3 += bf2f(b.w);
  }
  ushort4 o = make_ushort4(f2bf(a0), f2bf(a1), f2bf(a2), f2bf(a3));
  *(ushort4*)&agg[(size_t)v * 256 + c] = o;
}

// ---- down-path f32 GEMM (CIN=128 only) ----
template <bool GELU>
__global__ __launch_bounds__(256) void gemm_kernel(const float* __restrict__ A,
                                                   const float* __restrict__ W,
                                                   const float* __restrict__ bias,
                                                   float* __restrict__ out, int n) {
  __shared__ float As[64 * 32];
  __shared__ float Ws[32 * 128];
  int t = threadIdx.x;
  int row0 = blockIdx.x * 64;
  int colg = (t & 31) << 2;
  int rowg = t >> 5;
  float acc[8][4];
#pragma unroll
  for (int i = 0; i < 8; ++i)
#pragma unroll
    for (int j = 0; j < 4; ++j) acc[i][j] = 0.f;

  for (int k0 = 0; k0 < 128; k0 += 32) {
    __syncthreads();
#pragma unroll
    for (int l = 0; l < 2; ++l) {
      int id = t + l * 256;
      int ar = id >> 3, ac = (id & 7) << 2;
      float4 av = make_float4(0.f, 0.f, 0.f, 0.f);
      if (row0 + ar < n) av = *(const float4*)&A[(size_t)(row0 + ar) * 128 + k0 + ac];
      *(float4*)&As[ar * 32 + ac] = av;
    }
#pragma unroll
    for (int l = 0; l < 4; ++l) {
      int id = t + l * 256;
      int kk = id >> 5, wc = (id & 31) << 2;
      *(float4*)&Ws[kk * 128 + wc] = *(const float4*)&W[(size_t)(k0 + kk) * 128 + wc];
    }
    __syncthreads();
#pragma unroll
    for (int kk = 0; kk < 32; kk += 4) {
      float4 wv[4];
#pragma unroll
      for (int j = 0; j < 4; ++j) wv[j] = *(const float4*)&Ws[(kk + j) * 128 + colg];
#pragma unroll
      for (int i = 0; i < 8; ++i) {
        int rr = rowg + (i << 3);
        float4 av = *(const float4*)&As[rr * 32 + kk];
        acc[i][0] += av.x * wv[0].x + av.y * wv[1].x + av.z * wv[2].x + av.w * wv[3].x;
        acc[i][1] += av.x * wv[0].y + av.y * wv[1].y + av.z * wv[2].y + av.w * wv[3].y;
        acc[i][2] += av.x * wv[0].z + av.y * wv[1].z + av.z * wv[2].z + av.w * wv[3].z;
        acc[i][3] += av.x * wv[0].w + av.y * wv[1].w + av.z * wv[2].w + av.w * wv[3].w;
      }
    }
  }
  float4 bv = *(const float4*)&bias[colg];
#pragma unroll
  for (int i = 0; i < 8; ++i) {
    int rr = row0 + rowg + (i << 3);
    if (rr < n) {
      float4 o = make_float4(acc[i][0] + bv.x, acc[i][1] + bv.y, acc[i][2] + bv.z, acc[i][3] + bv.w);
      if (GELU) { o.x = gelu_f(o.x); o.y = gelu_f(o.y); o.z = gelu_f(o.z); o.w = gelu_f(o.w); }
      *(float4*)&out[(size_t)rr * 128 + colg] = o;
    }
  }
}

// ---- up-path MFMA GEMM: out[n,128] = act(A[n,K](bf16) @ W[K,128] + bias) ----
// WT is pre-transposed bf16 [128][K]. LDS stride 72 u16 keeps b128 reads bank-uniform.
template <int K, bool GELU, bool OUTBF>
__global__ __launch_bounds__(256) void gemm_mfma_kernel(const u16* __restrict__ A,
                                                        const u16* __restrict__ WT,
                                                        const float* __restrict__ bias,
                                                        void* __restrict__ out, int n) {
  __shared__ u16 As[64 * 72];
  __shared__ u16 Ws[128 * 72];
  int t = threadIdx.x;
  int lane = t & 63, wave = t >> 6;
  int row0 = blockIdx.x * 64;
  f32x4 acc[8];
#pragma unroll
  for (int i = 0; i < 8; ++i) acc[i] = (f32x4){0.f, 0.f, 0.f, 0.f};

  for (int k0 = 0; k0 < K; k0 += 64) {
    __syncthreads();
#pragma unroll
    for (int i = 0; i < 2; ++i) {  // A tile 64x64 bf16
      int c = t + i * 256;
      int r = c >> 3, seg = c & 7;
      bf16x8 v = {0, 0, 0, 0, 0, 0, 0, 0};
      if (row0 + r < n) v = *(const bf16x8*)&A[(size_t)(row0 + r) * K + k0 + seg * 8];
      *(bf16x8*)&As[r * 72 + seg * 8] = v;
    }
#pragma unroll
    for (int i = 0; i < 4; ++i) {  // WT tile 128x64 bf16
      int c = t + i * 256;
      int r = c >> 3, seg = c & 7;
      *(bf16x8*)&Ws[r * 72 + seg * 8] = *(const bf16x8*)&WT[(size_t)r * K + k0 + seg * 8];
    }
    __syncthreads();
#pragma unroll
    for (int kk = 0; kk < 64; kk += 32) {
      bf16x8 a = *(const bf16x8*)&As[(wave * 16 + (lane & 15)) * 72 + kk + (lane >> 4) * 8];
#pragma unroll
      for (int ct = 0; ct < 8; ++ct) {
        bf16x8 b = *(const bf16x8*)&Ws[(ct * 16 + (lane & 15)) * 72 + kk + (lane >> 4) * 8];
        acc[ct] = __builtin_amdgcn_mfma_f32_16x16x32_bf16(a, b, acc[ct], 0, 0, 0);
      }
    }
  }
  int colb = lane & 15, rquad = lane >> 4;
#pragma unroll
  for (int ct = 0; ct < 8; ++ct) {
#pragma unroll
    for (int r = 0; r < 4; ++r) {
      int row = row0 + wave * 16 + rquad * 4 + r;
      if (row < n) {
        int col = ct * 16 + colb;
        float v = acc[ct][r] + bias[col];
        if (GELU) v = gelu_f(v);
        if (OUTBF) ((u16*)out)[(size_t)row * 128 + col] = f2bf(v);
        else       ((float*)out)[(size_t)row * 128 + col] = v;
      }
    }
  }
}

// convert+transpose W [K][128] f32 -> WT [128][K] bf16
__global__ void wconv_kernel(const float* __restrict__ W, u16* __restrict__ WT, int K) {
  int i = blockIdx.x * 256 + threadIdx.x;
  if (i >= K * 128) return;
  int k = i >> 7, c = i & 127;
  WT[(size_t)c * K + k] = f2bf(W[i]);
}

__global__ void ln_kernel(const float* __restrict__ h, const float* __restrict__ g,
                          const float* __restrict__ beta, float* __restrict__ out, int n) {
  int wave = threadIdx.x >> 6, lane = threadIdx.x & 63;
  int i = blockIdx.x * 4 + wave;
  if (i >= n) return;
  float2 hv = *(const float2*)&h[(size_t)i * 128 + lane * 2];
  float s = hv.x + hv.y;
  for (int o = 32; o; o >>= 1) s += __shfl_down(s, o, 64);
  float mu = __shfl(s, 0, 64) * (1.0f / 128.0f);
  float dx = hv.x - mu, dy = hv.y - mu;
  float q = dx * dx + dy * dy;
  for (int o = 32; o; o >>= 1) q += __shfl_down(q, o, 64);
  float var = __shfl(q, 0, 64) * (1.0f / 128.0f);
  float rs = rsqrtf(var + 1e-5f);
  float2 gv = *(const float2*)&g[lane * 2];
  float2 bv = *(const float2*)&beta[lane * 2];
  float2 o2; o2.x = gv.x * dx * rs + bv.x; o2.y = gv.y * dy * rs + bv.y;
  *(float2*)&out[(size_t)i * 128 + lane * 2] = o2;
}

// cat (bf16): [:, :128] = res ; [:, 128:] = 0
__global__ void cat_res_bf_kernel(const float* __restrict__ res, u16* __restrict__ cat, int n) {
  int gid = blockIdx.x * 256 + threadIdx.x;
  int row = gid >> 6;
  if (row >= n) return;
  int q = gid & 63;
  int c = q << 2;
  if (q < 32) {
    float4 a = *(const float4*)&res[(size_t)row * 128 + c];
    *(ushort4*)&cat[(size_t)row * 256 + c] = make_ushort4(f2bf(a.x), f2bf(a.y), f2bf(a.z), f2bf(a.w));
  } else {
    *(ushort4*)&cat[(size_t)row * 256 + c] = make_ushort4(0, 0, 0, 0);
  }
}

// cat[perm[t], 128:] = xdeep[t, :]
__global__ void cat_up_bf_kernel(const float* __restrict__ xd, const int* __restrict__ perm,
                                 u16* __restrict__ cat, int k) {
  int gid = blockIdx.x * 256 + threadIdx.x;
  int t = gid >> 5;
  if (t >= k) return;
  int c = (gid & 31) << 2;
  float4 a = *(const float4*)&xd[(size_t)t * 128 + c];
  *(ushort4*)&cat[(size_t)perm[t] * 256 + 128 + c] =
      make_ushort4(f2bf(a.x), f2bf(a.y), f2bf(a.z), f2bf(a.w));
}

// ---------------------------------------------------------------------------

static inline int cdiv(int a, int b) { return (a + b - 1) / b; }

extern "C" void kernel_launch(void* const* d_in, const int* in_sizes, int n_in,
                              void* d_out, int out_size, void* d_ws, size_t ws_size,
                              hipStream_t stream) {
  const float* x0   = (const float*)d_in[0];
  const int*   snd  = (const int*)d_in[1];
  const int*   rcv  = (const int*)d_in[2];
  const float* poolw = (const float*)d_in[3];
  const float* dW1 = (const float*)d_in[4];
  const float* db1 = (const float*)d_in[5];
  const float* dW2 = (const float*)d_in[6];
  const float* db2 = (const float*)d_in[7];
  const float* dW3 = (const float*)d_in[8];
  const float* db3 = (const float*)d_in[9];
  const float* dg  = (const float*)d_in[10];
  const float* dbe = (const float*)d_in[11];
  const float* uW1 = (const float*)d_in[12];
  const float* ub1 = (const float*)d_in[13];
  const float* uW2 = (const float*)d_in[14];
  const float* ub2 = (const float*)d_in[15];
  const float* uW3 = (const float*)d_in[16];
  const float* ub3 = (const float*)d_in[17];
  const float* ug  = (const float*)d_in[18];
  const float* ube = (const float*)d_in[19];

  const int N0 = in_sizes[0] / 128;
  const int E  = in_sizes[1];
  const int N1 = (N0 + 1) / 2, N2 = (N1 + 1) / 2, N3 = (N2 + 1) / 2;

  // ---- workspace carve ----
  char* p = (char*)d_ws;
  auto alloc = [&](size_t bytes) -> void* {
    void* r = (void*)p;
    p += (bytes + 255) & ~(size_t)255;
    return r;
  };
  float* key  = (float*)alloc((size_t)N0 * 4);
  float* valt = (float*)alloc((size_t)N0 * 4);
  int*   hist = (int*)alloc(65536 * 4);
  int*   csum = (int*)alloc(256 * 4);
  int*   meta = (int*)alloc(64 * 4);
  int*   tcnt = (int*)alloc(512 * 4);
  int*   toff = (int*)alloc(512 * 4);
  unsigned char* selt = (unsigned char*)alloc((size_t)N0);
  int*   nmap = (int*)alloc((size_t)(N0 + 1) * 4);
  int*   perm0 = (int*)alloc((size_t)N1 * 4);
  int*   perm1 = (int*)alloc((size_t)N2 * 4);
  int*   perm2 = (int*)alloc((size_t)N3 * 4);
  float* vals  = (float*)alloc((size_t)N1 * 4);
  // edge lists (down only; h2b aliases this region during up)
  int* s1 = (int*)alloc((size_t)E * 4); int* r1 = (int*)alloc((size_t)E * 4);
  int* s2 = (int*)alloc((size_t)E * 4); int* r2 = (int*)alloc((size_t)E * 4);
  int* s3 = (int*)alloc((size_t)E * 4); int* r3 = (int*)alloc((size_t)E * 4);
  float* x1 = (float*)alloc((size_t)N1 * 128 * 4);
  float* x2 = (float*)alloc((size_t)N2 * 128 * 4);
  float* x3 = (float*)alloc((size_t)N3 * 128 * 4);
  float* xp = (float*)alloc((size_t)N1 * 128 * 4);   // down only; h1b aliases
  float* xu2 = (float*)alloc((size_t)N2 * 128 * 4);
  float* xu1 = (float*)alloc((size_t)N1 * 128 * 4);
  float* aggf = (float*)alloc((size_t)N1 * 128 * 4); // down agg out
  float* h1f  = (float*)alloc((size_t)N1 * 128 * 4); // down mlp scratch
  float* h2f  = (float*)alloc((size_t)N1 * 128 * 4);
  u16* agg_bf = (u16*)alloc((size_t)N0 * 256 * 2);   // up agg out
  u16* cat_bf = (u16*)alloc((size_t)N0 * 256 * 2);   // up cat; reused as f32 GEMM3 out
  u16* wt1 = (u16*)alloc((size_t)3 * 128 * 256 * 2);
  u16* wt2 = (u16*)alloc((size_t)3 * 128 * 128 * 2);
  u16* wt3 = (u16*)alloc((size_t)3 * 128 * 128 * 2);
  int* off0 = (int*)alloc((size_t)(N0 + 1) * 4); int* cur0 = (int*)alloc((size_t)N0 * 4);
  int* idx0 = (int*)alloc((size_t)2 * E * 4);
  int* off1 = (int*)alloc((size_t)(N1 + 1) * 4); int* cur1 = (int*)alloc((size_t)N1 * 4);
  int* idx1 = (int*)alloc((size_t)2 * E * 4);
  int* off2 = (int*)alloc((size_t)(N2 + 1) * 4); int* cur2 = (int*)alloc((size_t)N2 * 4);
  int* idx2 = (int*)alloc((size_t)2 * E * 4);
  int* off3 = (int*)alloc((size_t)(N3 + 1) * 4); int* cur3 = (int*)alloc((size_t)N3 * 4);
  int* idx3 = (int*)alloc((size_t)2 * E * 4);

  // phase-disjoint aliases (up-phase bf16 activations over dead down buffers)
  u16* h1b = (u16*)xp;              // N0*128*2 = 12.8MB over xp (12.8MB)
  u16* h2b = (u16*)s1;              // N0*128*2 = 12.8MB over s1..r3 (14.4MB)
  float* hfin = (float*)cat_bf;     // N0*128*4 = 25.6MB over cat_bf (25.6MB)

  // ---- weight convert/transpose (bf16, up path only) ----
  for (int l = 0; l < 3; ++l) {
    wconv_kernel<<<cdiv(256 * 128, 256), 256, 0, stream>>>(uW1 + (size_t)l * 256 * 128,
                                                           wt1 + (size_t)l * 128 * 256, 256);
    wconv_kernel<<<cdiv(128 * 128, 256), 256, 0, stream>>>(uW2 + (size_t)l * 128 * 128,
                                                           wt2 + (size_t)l * 128 * 128, 128);
    wconv_kernel<<<cdiv(128 * 128, 256), 256, 0, stream>>>(uW3 + (size_t)l * 128 * 128,
                                                           wt3 + (size_t)l * 128 * 128, 128);
  }

  // ---- level-0 CSR (for the final up step) ----
  hipMemsetAsync(cur0, 0, (size_t)N0 * 4, stream);
  deg_kernel<<<cdiv(E, 256), 256, 0, stream>>>(snd, rcv, cur0, E, N0);
  scan_kernel<<<1, 1024, 0, stream>>>(cur0, off0, cur0, N0);
  csr_scatter_kernel<<<cdiv(E, 256), 256, 0, stream>>>(snd, rcv, cur0, idx0, E, N0);

  // ---- generic down step (f32 exact; feeds top-k selection) ----
  auto down_step = [&](int n, int k, const float* xcur, const int* sin, const int* rin,
                       int* sout, int* rout, int* permL, float* xnext, int lvl,
                       int* offL, int* curL, int* idxL) {
    int nb = cdiv(n, 256);
    score_kernel<<<cdiv(n, 4), 256, 0, stream>>>(xcur, poolw + (size_t)lvl * 128, key, valt, n);
    hipMemsetAsync(hist, 0, 65536 * 4, stream);
    hist_hi_kernel<<<nb, 256, 0, stream>>>(key, hist, n);
    chunk_sum_kernel<<<256, 256, 0, stream>>>(hist, csum);
    find_hi2_kernel<<<1, 256, 0, stream>>>(hist, csum, meta, k);
    hipMemsetAsync(hist, 0, 65536 * 4, stream);
    hist_lo_kernel<<<nb, 256, 0, stream>>>(key, meta, hist, n);
    chunk_sum_kernel<<<256, 256, 0, stream>>>(hist, csum);
    find_lo2_kernel<<<1, 256, 0, stream>>>(hist, csum, meta);
    tie_count_kernel<<<nb, 256, 0, stream>>>(key, meta, tcnt, n);
    tie_scan_kernel<<<1, 256, 0, stream>>>(tcnt, toff, nb);
    tie_mark_kernel<<<nb, 256, 0, stream>>>(key, meta, toff, selt, n);
    select_kernel<<<cdiv(n + 1, 256), 256, 0, stream>>>(key, valt, selt, meta, permL, vals, nmap, n, k);
    pool_kernel<<<cdiv(k * 32, 256), 256, 0, stream>>>(xcur, permL, vals, xp, k);
    remap_kernel<<<cdiv(E, 256), 256, 0, stream>>>(sin, rin, nmap, sout, rout, E, k);
    hipMemsetAsync(curL, 0, (size_t)k * 4, stream);
    deg_kernel<<<cdiv(E, 256), 256, 0, stream>>>(sout, rout, curL, E, k);
    scan_kernel<<<1, 1024, 0, stream>>>(curL, offL, curL, k);
    csr_scatter_kernel<<<cdiv(E, 256), 256, 0, stream>>>(sout, rout, curL, idxL, E, k);
    agg_kernel<<<cdiv(k, 4), 256, 0, stream>>>(xp, offL, idxL, aggf, k);
    gemm_kernel<true><<<cdiv(k, 64), 256, 0, stream>>>(
        aggf, dW1 + (size_t)lvl * 128 * 128, db1 + (size_t)lvl * 128, h1f, k);
    gemm_kernel<true><<<cdiv(k, 64), 256, 0, stream>>>(
        h1f, dW2 + (size_t)lvl * 128 * 128, db2 + (size_t)lvl * 128, h2f, k);
    gemm_kernel<false><<<cdiv(k, 64), 256, 0, stream>>>(
        h2f, dW3 + (size_t)lvl * 128 * 128, db3 + (size_t)lvl * 128, h1f, k);
    ln_kernel<<<cdiv(k, 4), 256, 0, stream>>>(h1f, dg + (size_t)lvl * 128, dbe + (size_t)lvl * 128,
                                              xnext, k);
  };

  down_step(N0, N1, x0, snd, rcv, s1, r1, perm0, x1, 0, off1, cur1, idx1);
  down_step(N1, N2, x1, s1, r1, s2, r2, perm1, x2, 1, off2, cur2, idx2);
  down_step(N2, N3, x2, s2, r2, s3, r3, perm2, x3, 2, off3, cur3, idx3);

  // ---- generic up step (bf16 path) ----
  auto up_step = [&](int n, const float* res, const int* permL, const float* xdeep, int kdeep,
                     int lvl, const int* offL, const int* idxL, float* outbuf) {
    cat_res_bf_kernel<<<cdiv(n * 64, 256), 256, 0, stream>>>(res, cat_bf, n);
    cat_up_bf_kernel<<<cdiv(kdeep * 32, 256), 256, 0, stream>>>(xdeep, permL, cat_bf, kdeep);
    agg_bf_kernel<<<cdiv(n, 4), 256, 0, stream>>>(cat_bf, offL, idxL, agg_bf, n);
    gemm_mfma_kernel<256, true, true><<<cdiv(n, 64), 256, 0, stream>>>(
        agg_bf, wt1 + (size_t)lvl * 128 * 256, ub1 + (size_t)lvl * 128, h1b, n);
    gemm_mfma_kernel<128, true, true><<<cdiv(n, 64), 256, 0, stream>>>(
        h1b, wt2 + (size_t)lvl * 128 * 128, ub2 + (size_t)lvl * 128, h2b, n);
    gemm_mfma_kernel<128, false, false><<<cdiv(n, 64), 256, 0, stream>>>(
        h2b, wt3 + (size_t)lvl * 128 * 128, ub3 + (size_t)lvl * 128, hfin, n);  // cat_bf dead
    ln_kernel<<<cdiv(n, 4), 256, 0, stream>>>(hfin, ug + (size_t)lvl * 128, ube + (size_t)lvl * 128,
                                              outbuf, n);
  };

  up_step(N2, x2, perm2, x3, N3, 0, off2, idx2, xu2);
  up_step(N1, x1, perm1, xu2, N2, 1, off1, idx1, xu1);
  up_step(N0, x0, perm0, xu1, N1, 2, off0, idx0, (float*)d_out);

  (void)n_in; (void)out_size; (void)ws_size;
}

// Round 4
// 1226.062 us; speedup vs baseline: 1.7844x; 1.1324x over previous
//
#include <hip/hip_runtime.h>
#include <math.h>

// ---------------------------------------------------------------------------
// MeshGraphUnet2 forward on gfx950.  Round 3: parallel 3-pass CSR scan
// (replaces 117us single-block scan). Up path bf16+MFMA, down path f32 exact.
// ---------------------------------------------------------------------------

typedef unsigned short u16;
typedef short bf16x8 __attribute__((ext_vector_type(8)));
typedef float f32x4 __attribute__((ext_vector_type(4)));

__device__ __forceinline__ unsigned int fkey(float f) {
  unsigned int b = __float_as_uint(f);
  return (b & 0x80000000u) ? ~b : (b | 0x80000000u);  // monotonic float->uint
}

__device__ __forceinline__ float gelu_f(float v) {
  return 0.5f * v * (1.0f + erff(v * 0.70710678118654752f));
}

__device__ __forceinline__ u16 f2bf(float f) {
  unsigned u = __float_as_uint(f);
  u = (u + 0x7FFFu + ((u >> 16) & 1u)) >> 16;  // round-nearest-even
  return (u16)u;
}
__device__ __forceinline__ float bf2f(u16 u) {
  return __uint_as_float(((unsigned)u) << 16);
}

// ---- scoring: key[i] = (float)(x[i,:] . w)  (f64 acc), valt[i] = tanh(dot/||w||)
__global__ void score_kernel(const float* __restrict__ x, const float* __restrict__ w,
                             float* __restrict__ key, float* __restrict__ valt, int n) {
  int wave = threadIdx.x >> 6, lane = threadIdx.x & 63;
  int i = blockIdx.x * 4 + wave;
  if (i >= n) return;
  float2 xv = *(const float2*)&x[(size_t)i * 128 + lane * 2];
  float2 wv = *(const float2*)&w[lane * 2];
  double d  = (double)xv.x * wv.x + (double)xv.y * wv.y;
  double nw = (double)wv.x * wv.x + (double)wv.y * wv.y;
  for (int o = 32; o; o >>= 1) { d += __shfl_down(d, o, 64); nw += __shfl_down(nw, o, 64); }
  if (lane == 0) {
    key[i]  = (float)d;
    valt[i] = (float)tanh(d / sqrt(nw));
  }
}

__global__ void hist_hi_kernel(const float* __restrict__ key, int* __restrict__ hist, int n) {
  int i = blockIdx.x * 256 + threadIdx.x;
  if (i >= n) return;
  atomicAdd(&hist[fkey(key[i]) >> 16], 1);
}

__global__ void hist_lo_kernel(const float* __restrict__ key, const int* __restrict__ meta,
                               int* __restrict__ hist, int n) {
  int i = blockIdx.x * 256 + threadIdx.x;
  if (i >= n) return;
  unsigned u = fkey(key[i]);
  if ((u >> 16) == (unsigned)meta[0]) atomicAdd(&hist[u & 0xFFFFu], 1);
}

__global__ void chunk_sum_kernel(const int* __restrict__ hist, int* __restrict__ csum) {
  __shared__ int l[256];
  l[threadIdx.x] = hist[blockIdx.x * 256 + threadIdx.x];
  __syncthreads();
  for (int s = 128; s; s >>= 1) {
    if (threadIdx.x < s) l[threadIdx.x] += l[threadIdx.x + s];
    __syncthreads();
  }
  if (threadIdx.x == 0) csum[blockIdx.x] = l[0];
}

__global__ void find_hi2_kernel(const int* __restrict__ hist, const int* __restrict__ csum,
                                int* __restrict__ meta, int k) {
  __shared__ int s[256];
  __shared__ int cSh, cumSh;
  int t = threadIdx.x;
  s[t] = csum[t];
  __syncthreads();
  if (t == 0) {
    int cum = 0, c = 0;
    for (int i = 255; i >= 0; --i) {
      if (cum + s[i] >= k) { c = i; break; }
      cum += s[i];
    }
    cSh = c; cumSh = cum;
  }
  __syncthreads();
  int c = cSh;
  s[t] = hist[c * 256 + t];
  __syncthreads();
  if (t == 0) {
    int cum = cumSh;
    for (int b = 255; b >= 0; --b) {
      int v = s[b];
      if (cum + v >= k) { meta[0] = c * 256 + b; meta[1] = k - cum; break; }
      cum += v;
    }
  }
}

__global__ void find_lo2_kernel(const int* __restrict__ hist, const int* __restrict__ csum,
                                int* __restrict__ meta) {
  __shared__ int s[256];
  __shared__ int cSh, cumSh;
  int t = threadIdx.x;
  int m = meta[1], B = meta[0];
  s[t] = csum[t];
  __syncthreads();
  if (t == 0) {
    int cum = 0, c = 0;
    for (int i = 255; i >= 0; --i) {
      if (cum + s[i] >= m) { c = i; break; }
      cum += s[i];
    }
    cSh = c; cumSh = cum;
  }
  __syncthreads();
  int c = cSh;
  s[t] = hist[c * 256 + t];
  __syncthreads();
  if (t == 0) {
    int cum = cumSh;
    for (int b = 255; b >= 0; --b) {
      int v = s[b];
      if (cum + v >= m) {
        meta[3] = (int)((((unsigned)B) << 16) | (unsigned)(c * 256 + b));
        meta[4] = m - cum;
        break;
      }
      cum += v;
    }
    meta[5] = 0;
  }
}

__global__ void tie_count_kernel(const float* __restrict__ key, const int* __restrict__ meta,
                                 int* __restrict__ tcnt, int n) {
  __shared__ int cnt[4];
  unsigned uT = (unsigned)meta[3];
  int i = blockIdx.x * 256 + threadIdx.x;
  bool tie = (i < n) && (fkey(key[i]) == uT);
  unsigned long long m = __ballot(tie);
  int lane = threadIdx.x & 63, w = threadIdx.x >> 6;
  if (lane == 0) cnt[w] = __popcll(m);
  __syncthreads();
  if (threadIdx.x == 0) tcnt[blockIdx.x] = cnt[0] + cnt[1] + cnt[2] + cnt[3];
}

__global__ void tie_scan_kernel(const int* __restrict__ tcnt, int* __restrict__ toff, int nb) {
  __shared__ int l[512];
  int t = threadIdx.x;
  for (int b = t; b < nb; b += 256) l[b] = tcnt[b];
  __syncthreads();
  if (t == 0) {
    int c = 0;
    for (int b = 0; b < nb; ++b) { int v = l[b]; l[b] = c; c += v; }
  }
  __syncthreads();
  for (int b = t; b < nb; b += 256) toff[b] = l[b];
}

__global__ void tie_mark_kernel(const float* __restrict__ key, const int* __restrict__ meta,
                                const int* __restrict__ toff, unsigned char* __restrict__ selt,
                                int n) {
  __shared__ int woff[4];
  unsigned uT = (unsigned)meta[3];
  int tsel = meta[4];
  int i = blockIdx.x * 256 + threadIdx.x;
  bool tie = (i < n) && (fkey(key[i]) == uT);
  unsigned long long m = __ballot(tie);
  int lane = threadIdx.x & 63, w = threadIdx.x >> 6;
  if (lane == 0) woff[w] = __popcll(m);
  __syncthreads();
  if (threadIdx.x == 0) {
    int c = 0;
    for (int q = 0; q < 4; ++q) { int v = woff[q]; woff[q] = c; c += v; }
  }
  __syncthreads();
  if (tie) {
    int pre = __popcll(m & ((1ull << lane) - 1ull));
    int rank = toff[blockIdx.x] + woff[w] + pre;
    selt[i] = (rank < tsel) ? 1 : 0;
  }
}

__global__ void select_kernel(const float* __restrict__ key, const float* __restrict__ valt,
                              const unsigned char* __restrict__ selt, int* __restrict__ meta,
                              int* __restrict__ perm, float* __restrict__ vals,
                              int* __restrict__ nmap, int n, int k) {
  int i = blockIdx.x * 256 + threadIdx.x;
  if (i > n) return;
  if (i == n) { nmap[n] = k; return; }
  unsigned u  = fkey(key[i]);
  unsigned uT = (unsigned)meta[3];
  bool sel = (u > uT) || (u == uT && selt[i] != 0);
  if (sel) {
    int slot = atomicAdd(&meta[5], 1);
    perm[slot] = i; vals[slot] = valt[i]; nmap[i] = slot;
  } else {
    nmap[i] = k;
  }
}

__global__ void pool_kernel(const float* __restrict__ x, const int* __restrict__ perm,
                            const float* __restrict__ vals, float* __restrict__ xp, int k) {
  int gid = blockIdx.x * 256 + threadIdx.x;
  int t = gid >> 5;
  if (t >= k) return;
  int c = (gid & 31) << 2;
  float v = vals[t];
  float4 a = *(const float4*)&x[(size_t)perm[t] * 128 + c];
  a.x *= v; a.y *= v; a.z *= v; a.w *= v;
  *(float4*)&xp[(size_t)t * 128 + c] = a;
}

__global__ void remap_kernel(const int* __restrict__ s_in, const int* __restrict__ r_in,
                             const int* __restrict__ nmap, int* __restrict__ s_out,
                             int* __restrict__ r_out, int E, int k) {
  int e = blockIdx.x * 256 + threadIdx.x;
  if (e >= E) return;
  int a = nmap[s_in[e]], b = nmap[r_in[e]];
  if (a == k || b == k) { a = k; b = k; }
  s_out[e] = a; r_out[e] = b;
}

// ---- CSR build ----
__global__ void deg_kernel(const int* __restrict__ s, const int* __restrict__ r,
                           int* __restrict__ deg, int E, int n) {
  int e = blockIdx.x * 256 + threadIdx.x;
  if (e >= E) return;
  int ss = s[e];
  if (ss >= n) return;
  int rr = r[e];
  atomicAdd(&deg[rr], 1);
  atomicAdd(&deg[ss], 1);
}

// ---- 3-pass parallel exclusive scan (deg may alias cur) ----
__global__ void scan_part_kernel(const int* __restrict__ deg, int* __restrict__ bsum, int n) {
  __shared__ int l[256];
  int i = blockIdx.x * 256 + threadIdx.x;
  l[threadIdx.x] = (i < n) ? deg[i] : 0;
  __syncthreads();
  for (int s = 128; s; s >>= 1) {
    if (threadIdx.x < s) l[threadIdx.x] += l[threadIdx.x + s];
    __syncthreads();
  }
  if (threadIdx.x == 0) bsum[blockIdx.x] = l[0];
}

// single tiny block: exclusive scan of nb (<=256) block sums in place
__global__ void scan_bsum_kernel(int* __restrict__ bsum, int nb) {
  __shared__ int l[256];
  int t = threadIdx.x;
  l[t] = (t < nb) ? bsum[t] : 0;
  __syncthreads();
  if (t == 0) {
    int c = 0;
    for (int b = 0; b < nb; ++b) { int v = l[b]; l[b] = c; c += v; }
  }
  __syncthreads();
  if (t < nb) bsum[t] = l[t];
}

__global__ void scan_final_kernel(const int* __restrict__ deg, const int* __restrict__ bsum,
                                  int* __restrict__ off, int* __restrict__ cur, int n) {
  __shared__ int l[256];
  int i = blockIdx.x * 256 + threadIdx.x;
  int t = threadIdx.x;
  int v = (i < n) ? deg[i] : 0;
  l[t] = v;
  __syncthreads();
#pragma unroll
  for (int s = 1; s < 256; s <<= 1) {
    int add = (t >= s) ? l[t - s] : 0;
    __syncthreads();
    l[t] += add;
    __syncthreads();
  }
  int incl = l[t];
  int base = bsum[blockIdx.x];
  if (i < n) {
    int e = base + incl - v;
    off[i] = e; cur[i] = e;
    if (i == n - 1) off[n] = base + incl;
  }
}

__global__ void csr_scatter_kernel(const int* __restrict__ s, const int* __restrict__ r,
                                   int* __restrict__ cur, int* __restrict__ idx, int E, int n) {
  int e = blockIdx.x * 256 + threadIdx.x;
  if (e >= E) return;
  int ss = s[e];
  if (ss >= n) return;
  int rr = r[e];
  idx[atomicAdd(&cur[rr], 1)] = ss;
  idx[atomicAdd(&cur[ss], 1)] = rr;
}

// ---- down-path f32 aggregation (C=128) ----
__global__ void agg_kernel(const float* __restrict__ x, const int* __restrict__ off,
                           const int* __restrict__ idx, float* __restrict__ agg, int n) {
  int wave = threadIdx.x >> 6, lane = threadIdx.x & 63;
  int v = blockIdx.x * 4 + wave;
  if (v >= n) return;
  int lo = off[v], hi = off[v + 1];
  int c = lane * 2;
  float ax = 0.f, ay = 0.f;
  int j = lo;
  for (; j + 4 <= hi; j += 4) {
    int u0 = idx[j], u1 = idx[j + 1], u2 = idx[j + 2], u3 = idx[j + 3];
    float2 a0 = *(const float2*)&x[(size_t)u0 * 128 + c];
    float2 a1 = *(const float2*)&x[(size_t)u1 * 128 + c];
    float2 a2 = *(const float2*)&x[(size_t)u2 * 128 + c];
    float2 a3 = *(const float2*)&x[(size_t)u3 * 128 + c];
    ax += a0.x + a1.x + a2.x + a3.x;
    ay += a0.y + a1.y + a2.y + a3.y;
  }
  for (; j < hi; ++j) {
    int u = idx[j];
    float2 a = *(const float2*)&x[(size_t)u * 128 + c];
    ax += a.x; ay += a.y;
  }
  float2 o; o.x = ax; o.y = ay;
  *(float2*)&agg[(size_t)v * 128 + c] = o;
}

// ---- up-path bf16 aggregation (C=256 bf16 in, bf16 out, f32 accum) ----
__global__ void agg_bf_kernel(const u16* __restrict__ x, const int* __restrict__ off,
                              const int* __restrict__ idx, u16* __restrict__ agg, int n) {
  int wave = threadIdx.x >> 6, lane = threadIdx.x & 63;
  int v = blockIdx.x * 4 + wave;
  if (v >= n) return;
  int lo = off[v], hi = off[v + 1];
  int c = lane * 4;
  float a0 = 0.f, a1 = 0.f, a2 = 0.f, a3 = 0.f;
  int j = lo;
  for (; j + 8 <= hi; j += 8) {
    int us[8];
#pragma unroll
    for (int q = 0; q < 8; ++q) us[q] = idx[j + q];
#pragma unroll
    for (int q = 0; q < 8; ++q) {
      ushort4 b = *(const ushort4*)&x[(size_t)us[q] * 256 + c];
      a0 += bf2f(b.x); a1 += bf2f(b.y); a2 += bf2f(b.z); a3 += bf2f(b.w);
    }
  }
  for (; j < hi; ++j) {
    ushort4 b = *(const ushort4*)&x[(size_t)idx[j] * 256 + c];
    a0 += bf2f(b.x); a1 += bf2f(b.y); a2 += bf2f(b.z); a3 += bf2f(b.w);
  }
  ushort4 o = make_ushort4(f2bf(a0), f2bf(a1), f2bf(a2), f2bf(a3));
  *(ushort4*)&agg[(size_t)v * 256 + c] = o;
}

// ---- down-path f32 GEMM (CIN=128 only) ----
template <bool GELU>
__global__ __launch_bounds__(256) void gemm_kernel(const float* __restrict__ A,
                                                   const float* __restrict__ W,
                                                   const float* __restrict__ bias,
                                                   float* __restrict__ out, int n) {
  __shared__ float As[64 * 32];
  __shared__ float Ws[32 * 128];
  int t = threadIdx.x;
  int row0 = blockIdx.x * 64;
  int colg = (t & 31) << 2;
  int rowg = t >> 5;
  float acc[8][4];
#pragma unroll
  for (int i = 0; i < 8; ++i)
#pragma unroll
    for (int j = 0; j < 4; ++j) acc[i][j] = 0.f;

  for (int k0 = 0; k0 < 128; k0 += 32) {
    __syncthreads();
#pragma unroll
    for (int l = 0; l < 2; ++l) {
      int id = t + l * 256;
      int ar = id >> 3, ac = (id & 7) << 2;
      float4 av = make_float4(0.f, 0.f, 0.f, 0.f);
      if (row0 + ar < n) av = *(const float4*)&A[(size_t)(row0 + ar) * 128 + k0 + ac];
      *(float4*)&As[ar * 32 + ac] = av;
    }
#pragma unroll
    for (int l = 0; l < 4; ++l) {
      int id = t + l * 256;
      int kk = id >> 5, wc = (id & 31) << 2;
      *(float4*)&Ws[kk * 128 + wc] = *(const float4*)&W[(size_t)(k0 + kk) * 128 + wc];
    }
    __syncthreads();
#pragma unroll
    for (int kk = 0; kk < 32; kk += 4) {
      float4 wv[4];
#pragma unroll
      for (int j = 0; j < 4; ++j) wv[j] = *(const float4*)&Ws[(kk + j) * 128 + colg];
#pragma unroll
      for (int i = 0; i < 8; ++i) {
        int rr = rowg + (i << 3);
        float4 av = *(const float4*)&As[rr * 32 + kk];
        acc[i][0] += av.x * wv[0].x + av.y * wv[1].x + av.z * wv[2].x + av.w * wv[3].x;
        acc[i][1] += av.x * wv[0].y + av.y * wv[1].y + av.z * wv[2].y + av.w * wv[3].y;
        acc[i][2] += av.x * wv[0].z + av.y * wv[1].z + av.z * wv[2].z + av.w * wv[3].z;
        acc[i][3] += av.x * wv[0].w + av.y * wv[1].w + av.z * wv[2].w + av.w * wv[3].w;
      }
    }
  }
  float4 bv = *(const float4*)&bias[colg];
#pragma unroll
  for (int i = 0; i < 8; ++i) {
    int rr = row0 + rowg + (i << 3);
    if (rr < n) {
      float4 o = make_float4(acc[i][0] + bv.x, acc[i][1] + bv.y, acc[i][2] + bv.z, acc[i][3] + bv.w);
      if (GELU) { o.x = gelu_f(o.x); o.y = gelu_f(o.y); o.z = gelu_f(o.z); o.w = gelu_f(o.w); }
      *(float4*)&out[(size_t)rr * 128 + colg] = o;
    }
  }
}

// ---- up-path MFMA GEMM: out[n,128] = act(A[n,K](bf16) @ W[K,128] + bias) ----
template <int K, bool GELU, bool OUTBF>
__global__ __launch_bounds__(256) void gemm_mfma_kernel(const u16* __restrict__ A,
                                                        const u16* __restrict__ WT,
                                                        const float* __restrict__ bias,
                                                        void* __restrict__ out, int n) {
  __shared__ u16 As[64 * 72];
  __shared__ u16 Ws[128 * 72];
  int t = threadIdx.x;
  int lane = t & 63, wave = t >> 6;
  int row0 = blockIdx.x * 64;
  f32x4 acc[8];
#pragma unroll
  for (int i = 0; i < 8; ++i) acc[i] = (f32x4){0.f, 0.f, 0.f, 0.f};

  for (int k0 = 0; k0 < K; k0 += 64) {
    __syncthreads();
#pragma unroll
    for (int i = 0; i < 2; ++i) {  // A tile 64x64 bf16
      int c = t + i * 256;
      int r = c >> 3, seg = c & 7;
      bf16x8 v = {0, 0, 0, 0, 0, 0, 0, 0};
      if (row0 + r < n) v = *(const bf16x8*)&A[(size_t)(row0 + r) * K + k0 + seg * 8];
      *(bf16x8*)&As[r * 72 + seg * 8] = v;
    }
#pragma unroll
    for (int i = 0; i < 4; ++i) {  // WT tile 128x64 bf16
      int c = t + i * 256;
      int r = c >> 3, seg = c & 7;
      *(bf16x8*)&Ws[r * 72 + seg * 8] = *(const bf16x8*)&WT[(size_t)r * K + k0 + seg * 8];
    }
    __syncthreads();
#pragma unroll
    for (int kk = 0; kk < 64; kk += 32) {
      bf16x8 a = *(const bf16x8*)&As[(wave * 16 + (lane & 15)) * 72 + kk + (lane >> 4) * 8];
#pragma unroll
      for (int ct = 0; ct < 8; ++ct) {
        bf16x8 b = *(const bf16x8*)&Ws[(ct * 16 + (lane & 15)) * 72 + kk + (lane >> 4) * 8];
        acc[ct] = __builtin_amdgcn_mfma_f32_16x16x32_bf16(a, b, acc[ct], 0, 0, 0);
      }
    }
  }
  int colb = lane & 15, rquad = lane >> 4;
#pragma unroll
  for (int ct = 0; ct < 8; ++ct) {
#pragma unroll
    for (int r = 0; r < 4; ++r) {
      int row = row0 + wave * 16 + rquad * 4 + r;
      if (row < n) {
        int col = ct * 16 + colb;
        float v = acc[ct][r] + bias[col];
        if (GELU) v = gelu_f(v);
        if (OUTBF) ((u16*)out)[(size_t)row * 128 + col] = f2bf(v);
        else       ((float*)out)[(size_t)row * 128 + col] = v;
      }
    }
  }
}

// convert+transpose W [K][128] f32 -> WT [128][K] bf16
__global__ void wconv_kernel(const float* __restrict__ W, u16* __restrict__ WT, int K) {
  int i = blockIdx.x * 256 + threadIdx.x;
  if (i >= K * 128) return;
  int k = i >> 7, c = i & 127;
  WT[(size_t)c * K + k] = f2bf(W[i]);
}

__global__ void ln_kernel(const float* __restrict__ h, const float* __restrict__ g,
                          const float* __restrict__ beta, float* __restrict__ out, int n) {
  int wave = threadIdx.x >> 6, lane = threadIdx.x & 63;
  int i = blockIdx.x * 4 + wave;
  if (i >= n) return;
  float2 hv = *(const float2*)&h[(size_t)i * 128 + lane * 2];
  float s = hv.x + hv.y;
  for (int o = 32; o; o >>= 1) s += __shfl_down(s, o, 64);
  float mu = __shfl(s, 0, 64) * (1.0f / 128.0f);
  float dx = hv.x - mu, dy = hv.y - mu;
  float q = dx * dx + dy * dy;
  for (int o = 32; o; o >>= 1) q += __shfl_down(q, o, 64);
  float var = __shfl(q, 0, 64) * (1.0f / 128.0f);
  float rs = rsqrtf(var + 1e-5f);
  float2 gv = *(const float2*)&g[lane * 2];
  float2 bv = *(const float2*)&beta[lane * 2];
  float2 o2; o2.x = gv.x * dx * rs + bv.x; o2.y = gv.y * dy * rs + bv.y;
  *(float2*)&out[(size_t)i * 128 + lane * 2] = o2;
}

// cat (bf16): [:, :128] = res ; [:, 128:] = 0
__global__ void cat_res_bf_kernel(const float* __restrict__ res, u16* __restrict__ cat, int n) {
  int gid = blockIdx.x * 256 + threadIdx.x;
  int row = gid >> 6;
  if (row >= n) return;
  int q = gid & 63;
  int c = q << 2;
  if (q < 32) {
    float4 a = *(const float4*)&res[(size_t)row * 128 + c];
    *(ushort4*)&cat[(size_t)row * 256 + c] = make_ushort4(f2bf(a.x), f2bf(a.y), f2bf(a.z), f2bf(a.w));
  } else {
    *(ushort4*)&cat[(size_t)row * 256 + c] = make_ushort4(0, 0, 0, 0);
  }
}

// cat[perm[t], 128:] = xdeep[t, :]
__global__ void cat_up_bf_kernel(const float* __restrict__ xd, const int* __restrict__ perm,
                                 u16* __restrict__ cat, int k) {
  int gid = blockIdx.x * 256 + threadIdx.x;
  int t = gid >> 5;
  if (t >= k) return;
  int c = (gid & 31) << 2;
  float4 a = *(const float4*)&xd[(size_t)t * 128 + c];
  *(ushort4*)&cat[(size_t)perm[t] * 256 + 128 + c] =
      make_ushort4(f2bf(a.x), f2bf(a.y), f2bf(a.z), f2bf(a.w));
}

// ---------------------------------------------------------------------------

static inline int cdiv(int a, int b) { return (a + b - 1) / b; }

extern "C" void kernel_launch(void* const* d_in, const int* in_sizes, int n_in,
                              void* d_out, int out_size, void* d_ws, size_t ws_size,
                              hipStream_t stream) {
  const float* x0   = (const float*)d_in[0];
  const int*   snd  = (const int*)d_in[1];
  const int*   rcv  = (const int*)d_in[2];
  const float* poolw = (const float*)d_in[3];
  const float* dW1 = (const float*)d_in[4];
  const float* db1 = (const float*)d_in[5];
  const float* dW2 = (const float*)d_in[6];
  const float* db2 = (const float*)d_in[7];
  const float* dW3 = (const float*)d_in[8];
  const float* db3 = (const float*)d_in[9];
  const float* dg  = (const float*)d_in[10];
  const float* dbe = (const float*)d_in[11];
  const float* uW1 = (const float*)d_in[12];
  const float* ub1 = (const float*)d_in[13];
  const float* uW2 = (const float*)d_in[14];
  const float* ub2 = (const float*)d_in[15];
  const float* uW3 = (const float*)d_in[16];
  const float* ub3 = (const float*)d_in[17];
  const float* ug  = (const float*)d_in[18];
  const float* ube = (const float*)d_in[19];

  const int N0 = in_sizes[0] / 128;
  const int E  = in_sizes[1];
  const int N1 = (N0 + 1) / 2, N2 = (N1 + 1) / 2, N3 = (N2 + 1) / 2;

  // ---- workspace carve ----
  char* p = (char*)d_ws;
  auto alloc = [&](size_t bytes) -> void* {
    void* r = (void*)p;
    p += (bytes + 255) & ~(size_t)255;
    return r;
  };
  float* key  = (float*)alloc((size_t)N0 * 4);
  float* valt = (float*)alloc((size_t)N0 * 4);
  int*   hist = (int*)alloc(65536 * 4);
  int*   csum = (int*)alloc(256 * 4);
  int*   meta = (int*)alloc(64 * 4);
  int*   tcnt = (int*)alloc(512 * 4);
  int*   toff = (int*)alloc(512 * 4);
  int*   bsum = (int*)alloc(256 * 4);
  unsigned char* selt = (unsigned char*)alloc((size_t)N0);
  int*   nmap = (int*)alloc((size_t)(N0 + 1) * 4);
  int*   perm0 = (int*)alloc((size_t)N1 * 4);
  int*   perm1 = (int*)alloc((size_t)N2 * 4);
  int*   perm2 = (int*)alloc((size_t)N3 * 4);
  float* vals  = (float*)alloc((size_t)N1 * 4);
  // edge lists (down only; h2b aliases this region during up)
  int* s1 = (int*)alloc((size_t)E * 4); int* r1 = (int*)alloc((size_t)E * 4);
  int* s2 = (int*)alloc((size_t)E * 4); int* r2 = (int*)alloc((size_t)E * 4);
  int* s3 = (int*)alloc((size_t)E * 4); int* r3 = (int*)alloc((size_t)E * 4);
  float* x1 = (float*)alloc((size_t)N1 * 128 * 4);
  float* x2 = (float*)alloc((size_t)N2 * 128 * 4);
  float* x3 = (float*)alloc((size_t)N3 * 128 * 4);
  float* xp = (float*)alloc((size_t)N1 * 128 * 4);   // down only; h1b aliases
  float* xu2 = (float*)alloc((size_t)N2 * 128 * 4);
  float* xu1 = (float*)alloc((size_t)N1 * 128 * 4);
  float* aggf = (float*)alloc((size_t)N1 * 128 * 4); // down agg out
  float* h1f  = (float*)alloc((size_t)N1 * 128 * 4); // down mlp scratch
  float* h2f  = (float*)alloc((size_t)N1 * 128 * 4);
  u16* agg_bf = (u16*)alloc((size_t)N0 * 256 * 2);   // up agg out
  u16* cat_bf = (u16*)alloc((size_t)N0 * 256 * 2);   // up cat; reused as f32 GEMM3 out
  u16* wt1 = (u16*)alloc((size_t)3 * 128 * 256 * 2);
  u16* wt2 = (u16*)alloc((size_t)3 * 128 * 128 * 2);
  u16* wt3 = (u16*)alloc((size_t)3 * 128 * 128 * 2);
  int* off0 = (int*)alloc((size_t)(N0 + 1) * 4); int* cur0 = (int*)alloc((size_t)N0 * 4);
  int* idx0 = (int*)alloc((size_t)2 * E * 4);
  int* off1 = (int*)alloc((size_t)(N1 + 1) * 4); int* cur1 = (int*)alloc((size_t)N1 * 4);
  int* idx1 = (int*)alloc((size_t)2 * E * 4);
  int* off2 = (int*)alloc((size_t)(N2 + 1) * 4); int* cur2 = (int*)alloc((size_t)N2 * 4);
  int* idx2 = (int*)alloc((size_t)2 * E * 4);
  int* off3 = (int*)alloc((size_t)(N3 + 1) * 4); int* cur3 = (int*)alloc((size_t)N3 * 4);
  int* idx3 = (int*)alloc((size_t)2 * E * 4);

  // phase-disjoint aliases (up-phase bf16 activations over dead down buffers)
  u16* h1b = (u16*)xp;              // N0*128*2 = 12.8MB over xp (12.8MB)
  u16* h2b = (u16*)s1;              // N0*128*2 = 12.8MB over s1..r3 (14.4MB)
  float* hfin = (float*)cat_bf;     // N0*128*4 = 25.6MB over cat_bf (25.6MB)

  // parallel exclusive scan: deg in cur[0..n), writes off[0..n] and cur
  auto run_scan = [&](int* curB, int* offB, int n) {
    int nb = cdiv(n, 256);
    scan_part_kernel<<<nb, 256, 0, stream>>>(curB, bsum, n);
    scan_bsum_kernel<<<1, 256, 0, stream>>>(bsum, nb);
    scan_final_kernel<<<nb, 256, 0, stream>>>(curB, bsum, offB, curB, n);
  };

  // ---- weight convert/transpose (bf16, up path only) ----
  for (int l = 0; l < 3; ++l) {
    wconv_kernel<<<cdiv(256 * 128, 256), 256, 0, stream>>>(uW1 + (size_t)l * 256 * 128,
                                                           wt1 + (size_t)l * 128 * 256, 256);
    wconv_kernel<<<cdiv(128 * 128, 256), 256, 0, stream>>>(uW2 + (size_t)l * 128 * 128,
                                                           wt2 + (size_t)l * 128 * 128, 128);
    wconv_kernel<<<cdiv(128 * 128, 256), 256, 0, stream>>>(uW3 + (size_t)l * 128 * 128,
                                                           wt3 + (size_t)l * 128 * 128, 128);
  }

  // ---- level-0 CSR (for the final up step) ----
  hipMemsetAsync(cur0, 0, (size_t)N0 * 4, stream);
  deg_kernel<<<cdiv(E, 256), 256, 0, stream>>>(snd, rcv, cur0, E, N0);
  run_scan(cur0, off0, N0);
  csr_scatter_kernel<<<cdiv(E, 256), 256, 0, stream>>>(snd, rcv, cur0, idx0, E, N0);

  // ---- generic down step (f32 exact; feeds top-k selection) ----
  auto down_step = [&](int n, int k, const float* xcur, const int* sin, const int* rin,
                       int* sout, int* rout, int* permL, float* xnext, int lvl,
                       int* offL, int* curL, int* idxL) {
    int nb = cdiv(n, 256);
    score_kernel<<<cdiv(n, 4), 256, 0, stream>>>(xcur, poolw + (size_t)lvl * 128, key, valt, n);
    hipMemsetAsync(hist, 0, 65536 * 4, stream);
    hist_hi_kernel<<<nb, 256, 0, stream>>>(key, hist, n);
    chunk_sum_kernel<<<256, 256, 0, stream>>>(hist, csum);
    find_hi2_kernel<<<1, 256, 0, stream>>>(hist, csum, meta, k);
    hipMemsetAsync(hist, 0, 65536 * 4, stream);
    hist_lo_kernel<<<nb, 256, 0, stream>>>(key, meta, hist, n);
    chunk_sum_kernel<<<256, 256, 0, stream>>>(hist, csum);
    find_lo2_kernel<<<1, 256, 0, stream>>>(hist, csum, meta);
    tie_count_kernel<<<nb, 256, 0, stream>>>(key, meta, tcnt, n);
    tie_scan_kernel<<<1, 256, 0, stream>>>(tcnt, toff, nb);
    tie_mark_kernel<<<nb, 256, 0, stream>>>(key, meta, toff, selt, n);
    select_kernel<<<cdiv(n + 1, 256), 256, 0, stream>>>(key, valt, selt, meta, permL, vals, nmap, n, k);
    pool_kernel<<<cdiv(k * 32, 256), 256, 0, stream>>>(xcur, permL, vals, xp, k);
    remap_kernel<<<cdiv(E, 256), 256, 0, stream>>>(sin, rin, nmap, sout, rout, E, k);
    hipMemsetAsync(curL, 0, (size_t)k * 4, stream);
    deg_kernel<<<cdiv(E, 256), 256, 0, stream>>>(sout, rout, curL, E, k);
    run_scan(curL, offL, k);
    csr_scatter_kernel<<<cdiv(E, 256), 256, 0, stream>>>(sout, rout, curL, idxL, E, k);
    agg_kernel<<<cdiv(k, 4), 256, 0, stream>>>(xp, offL, idxL, aggf, k);
    gemm_kernel<true><<<cdiv(k, 64), 256, 0, stream>>>(
        aggf, dW1 + (size_t)lvl * 128 * 128, db1 + (size_t)lvl * 128, h1f, k);
    gemm_kernel<true><<<cdiv(k, 64), 256, 0, stream>>>(
        h1f, dW2 + (size_t)lvl * 128 * 128, db2 + (size_t)lvl * 128, h2f, k);
    gemm_kernel<false><<<cdiv(k, 64), 256, 0, stream>>>(
        h2f, dW3 + (size_t)lvl * 128 * 128, db3 + (size_t)lvl * 128, h1f, k);
    ln_kernel<<<cdiv(k, 4), 256, 0, stream>>>(h1f, dg + (size_t)lvl * 128, dbe + (size_t)lvl * 128,
                                              xnext, k);
  };

  down_step(N0, N1, x0, snd, rcv, s1, r1, perm0, x1, 0, off1, cur1, idx1);
  down_step(N1, N2, x1, s1, r1, s2, r2, perm1, x2, 1, off2, cur2, idx2);
  down_step(N2, N3, x2, s2, r2, s3, r3, perm2, x3, 2, off3, cur3, idx3);

  // ---- generic up step (bf16 path) ----
  auto up_step = [&](int n, const float* res, const int* permL, const float* xdeep, int kdeep,
                     int lvl, const int* offL, const int* idxL, float* outbuf) {
    cat_res_bf_kernel<<<cdiv(n * 64, 256), 256, 0, stream>>>(res, cat_bf, n);
    cat_up_bf_kernel<<<cdiv(kdeep * 32, 256), 256, 0, stream>>>(xdeep, permL, cat_bf, kdeep);
    agg_bf_kernel<<<cdiv(n, 4), 256, 0, stream>>>(cat_bf, offL, idxL, agg_bf, n);
    gemm_mfma_kernel<256, true, true><<<cdiv(n, 64), 256, 0, stream>>>(
        agg_bf, wt1 + (size_t)lvl * 128 * 256, ub1 + (size_t)lvl * 128, h1b, n);
    gemm_mfma_kernel<128, true, true><<<cdiv(n, 64), 256, 0, stream>>>(
        h1b, wt2 + (size_t)lvl * 128 * 128, ub2 + (size_t)lvl * 128, h2b, n);
    gemm_mfma_kernel<128, false, false><<<cdiv(n, 64), 256, 0, stream>>>(
        h2b, wt3 + (size_t)lvl * 128 * 128, ub3 + (size_t)lvl * 128, hfin, n);  // cat_bf dead
    ln_kernel<<<cdiv(n, 4), 256, 0, stream>>>(hfin, ug + (size_t)lvl * 128, ube + (size_t)lvl * 128,
                                              outbuf, n);
  };

  up_step(N2, x2, perm2, x3, N3, 0, off2, idx2, xu2);
  up_step(N1, x1, perm1, xu2, N2, 1, off1, idx1, xu1);
  up_step(N0, x0, perm0, xu1, N1, 2, off0, idx0, (float*)d_out);

  (void)n_in; (void)out_size; (void)ws_size;
}

// Round 5
// 1101.104 us; speedup vs baseline: 1.9870x; 1.1135x over previous
//
#include <hip/hip_runtime.h>
#include <math.h>

// ---------------------------------------------------------------------------
// MeshGraphUnet2 forward on gfx950.  Round 4: XCD-partitioned CSR scatter
// (kills 17x write amplification), deg fused into remap, 32-row f32 GEMM tile,
// fused wconv. Up path bf16+MFMA, down path f32 exact.
// ---------------------------------------------------------------------------

typedef unsigned short u16;
typedef short bf16x8 __attribute__((ext_vector_type(8)));
typedef float f32x4 __attribute__((ext_vector_type(4)));

__device__ __forceinline__ unsigned int fkey(float f) {
  unsigned int b = __float_as_uint(f);
  return (b & 0x80000000u) ? ~b : (b | 0x80000000u);  // monotonic float->uint
}

__device__ __forceinline__ float gelu_f(float v) {
  return 0.5f * v * (1.0f + erff(v * 0.70710678118654752f));
}

__device__ __forceinline__ u16 f2bf(float f) {
  unsigned u = __float_as_uint(f);
  u = (u + 0x7FFFu + ((u >> 16) & 1u)) >> 16;  // round-nearest-even
  return (u16)u;
}
__device__ __forceinline__ float bf2f(u16 u) {
  return __uint_as_float(((unsigned)u) << 16);
}

// ---- scoring: key[i] = (float)(x[i,:] . w)  (f64 acc), valt[i] = tanh(dot/||w||)
__global__ void score_kernel(const float* __restrict__ x, const float* __restrict__ w,
                             float* __restrict__ key, float* __restrict__ valt, int n) {
  int wave = threadIdx.x >> 6, lane = threadIdx.x & 63;
  int i = blockIdx.x * 4 + wave;
  if (i >= n) return;
  float2 xv = *(const float2*)&x[(size_t)i * 128 + lane * 2];
  float2 wv = *(const float2*)&w[lane * 2];
  double d  = (double)xv.x * wv.x + (double)xv.y * wv.y;
  double nw = (double)wv.x * wv.x + (double)wv.y * wv.y;
  for (int o = 32; o; o >>= 1) { d += __shfl_down(d, o, 64); nw += __shfl_down(nw, o, 64); }
  if (lane == 0) {
    key[i]  = (float)d;
    valt[i] = (float)tanh(d / sqrt(nw));
  }
}

__global__ void hist_hi_kernel(const float* __restrict__ key, int* __restrict__ hist, int n) {
  int i = blockIdx.x * 256 + threadIdx.x;
  if (i >= n) return;
  atomicAdd(&hist[fkey(key[i]) >> 16], 1);
}

__global__ void hist_lo_kernel(const float* __restrict__ key, const int* __restrict__ meta,
                               int* __restrict__ hist, int n) {
  int i = blockIdx.x * 256 + threadIdx.x;
  if (i >= n) return;
  unsigned u = fkey(key[i]);
  if ((u >> 16) == (unsigned)meta[0]) atomicAdd(&hist[u & 0xFFFFu], 1);
}

__global__ void chunk_sum_kernel(const int* __restrict__ hist, int* __restrict__ csum) {
  __shared__ int l[256];
  l[threadIdx.x] = hist[blockIdx.x * 256 + threadIdx.x];
  __syncthreads();
  for (int s = 128; s; s >>= 1) {
    if (threadIdx.x < s) l[threadIdx.x] += l[threadIdx.x + s];
    __syncthreads();
  }
  if (threadIdx.x == 0) csum[blockIdx.x] = l[0];
}

__global__ void find_hi2_kernel(const int* __restrict__ hist, const int* __restrict__ csum,
                                int* __restrict__ meta, int k) {
  __shared__ int s[256];
  __shared__ int cSh, cumSh;
  int t = threadIdx.x;
  s[t] = csum[t];
  __syncthreads();
  if (t == 0) {
    int cum = 0, c = 0;
    for (int i = 255; i >= 0; --i) {
      if (cum + s[i] >= k) { c = i; break; }
      cum += s[i];
    }
    cSh = c; cumSh = cum;
  }
  __syncthreads();
  int c = cSh;
  s[t] = hist[c * 256 + t];
  __syncthreads();
  if (t == 0) {
    int cum = cumSh;
    for (int b = 255; b >= 0; --b) {
      int v = s[b];
      if (cum + v >= k) { meta[0] = c * 256 + b; meta[1] = k - cum; break; }
      cum += v;
    }
  }
}

__global__ void find_lo2_kernel(const int* __restrict__ hist, const int* __restrict__ csum,
                                int* __restrict__ meta) {
  __shared__ int s[256];
  __shared__ int cSh, cumSh;
  int t = threadIdx.x;
  int m = meta[1], B = meta[0];
  s[t] = csum[t];
  __syncthreads();
  if (t == 0) {
    int cum = 0, c = 0;
    for (int i = 255; i >= 0; --i) {
      if (cum + s[i] >= m) { c = i; break; }
      cum += s[i];
    }
    cSh = c; cumSh = cum;
  }
  __syncthreads();
  int c = cSh;
  s[t] = hist[c * 256 + t];
  __syncthreads();
  if (t == 0) {
    int cum = cumSh;
    for (int b = 255; b >= 0; --b) {
      int v = s[b];
      if (cum + v >= m) {
        meta[3] = (int)((((unsigned)B) << 16) | (unsigned)(c * 256 + b));
        meta[4] = m - cum;
        break;
      }
      cum += v;
    }
    meta[5] = 0;
  }
}

__global__ void tie_count_kernel(const float* __restrict__ key, const int* __restrict__ meta,
                                 int* __restrict__ tcnt, int n) {
  __shared__ int cnt[4];
  unsigned uT = (unsigned)meta[3];
  int i = blockIdx.x * 256 + threadIdx.x;
  bool tie = (i < n) && (fkey(key[i]) == uT);
  unsigned long long m = __ballot(tie);
  int lane = threadIdx.x & 63, w = threadIdx.x >> 6;
  if (lane == 0) cnt[w] = __popcll(m);
  __syncthreads();
  if (threadIdx.x == 0) tcnt[blockIdx.x] = cnt[0] + cnt[1] + cnt[2] + cnt[3];
}

__global__ void tie_scan_kernel(const int* __restrict__ tcnt, int* __restrict__ toff, int nb) {
  __shared__ int l[512];
  int t = threadIdx.x;
  for (int b = t; b < nb; b += 256) l[b] = tcnt[b];
  __syncthreads();
  if (t == 0) {
    int c = 0;
    for (int b = 0; b < nb; ++b) { int v = l[b]; l[b] = c; c += v; }
  }
  __syncthreads();
  for (int b = t; b < nb; b += 256) toff[b] = l[b];
}

__global__ void tie_mark_kernel(const float* __restrict__ key, const int* __restrict__ meta,
                                const int* __restrict__ toff, unsigned char* __restrict__ selt,
                                int n) {
  __shared__ int woff[4];
  unsigned uT = (unsigned)meta[3];
  int tsel = meta[4];
  int i = blockIdx.x * 256 + threadIdx.x;
  bool tie = (i < n) && (fkey(key[i]) == uT);
  unsigned long long m = __ballot(tie);
  int lane = threadIdx.x & 63, w = threadIdx.x >> 6;
  if (lane == 0) woff[w] = __popcll(m);
  __syncthreads();
  if (threadIdx.x == 0) {
    int c = 0;
    for (int q = 0; q < 4; ++q) { int v = woff[q]; woff[q] = c; c += v; }
  }
  __syncthreads();
  if (tie) {
    int pre = __popcll(m & ((1ull << lane) - 1ull));
    int rank = toff[blockIdx.x] + woff[w] + pre;
    selt[i] = (rank < tsel) ? 1 : 0;
  }
}

__global__ void select_kernel(const float* __restrict__ key, const float* __restrict__ valt,
                              const unsigned char* __restrict__ selt, int* __restrict__ meta,
                              int* __restrict__ perm, float* __restrict__ vals,
                              int* __restrict__ nmap, int n, int k) {
  int i = blockIdx.x * 256 + threadIdx.x;
  if (i > n) return;
  if (i == n) { nmap[n] = k; return; }
  unsigned u  = fkey(key[i]);
  unsigned uT = (unsigned)meta[3];
  bool sel = (u > uT) || (u == uT && selt[i] != 0);
  if (sel) {
    int slot = atomicAdd(&meta[5], 1);
    perm[slot] = i; vals[slot] = valt[i]; nmap[i] = slot;
  } else {
    nmap[i] = k;
  }
}

__global__ void pool_kernel(const float* __restrict__ x, const int* __restrict__ perm,
                            const float* __restrict__ vals, float* __restrict__ xp, int k) {
  int gid = blockIdx.x * 256 + threadIdx.x;
  int t = gid >> 5;
  if (t >= k) return;
  int c = (gid & 31) << 2;
  float v = vals[t];
  float4 a = *(const float4*)&x[(size_t)perm[t] * 128 + c];
  a.x *= v; a.y *= v; a.z *= v; a.w *= v;
  *(float4*)&xp[(size_t)t * 128 + c] = a;
}

// remap + degree count fused (deg must be zeroed before)
__global__ void remap_deg_kernel(const int* __restrict__ s_in, const int* __restrict__ r_in,
                                 const int* __restrict__ nmap, int* __restrict__ s_out,
                                 int* __restrict__ r_out, int* __restrict__ deg, int E, int k) {
  int e = blockIdx.x * 256 + threadIdx.x;
  if (e >= E) return;
  int a = nmap[s_in[e]], b = nmap[r_in[e]];
  if (a == k || b == k) { a = k; b = k; }
  s_out[e] = a; r_out[e] = b;
  if (a < k) { atomicAdd(&deg[b], 1); atomicAdd(&deg[a], 1); }
}

// ---- CSR build ----
__global__ void deg_kernel(const int* __restrict__ s, const int* __restrict__ r,
                           int* __restrict__ deg, int E, int n) {
  int e = blockIdx.x * 256 + threadIdx.x;
  if (e >= E) return;
  int ss = s[e];
  if (ss >= n) return;
  int rr = r[e];
  atomicAdd(&deg[rr], 1);
  atomicAdd(&deg[ss], 1);
}

// ---- 3-pass parallel exclusive scan (deg may alias cur) ----
__global__ void scan_part_kernel(const int* __restrict__ deg, int* __restrict__ bsum, int n) {
  __shared__ int l[256];
  int i = blockIdx.x * 256 + threadIdx.x;
  l[threadIdx.x] = (i < n) ? deg[i] : 0;
  __syncthreads();
  for (int s = 128; s; s >>= 1) {
    if (threadIdx.x < s) l[threadIdx.x] += l[threadIdx.x + s];
    __syncthreads();
  }
  if (threadIdx.x == 0) bsum[blockIdx.x] = l[0];
}

__global__ void scan_bsum_kernel(int* __restrict__ bsum, int nb) {
  __shared__ int l[256];
  int t = threadIdx.x;
  l[t] = (t < nb) ? bsum[t] : 0;
  __syncthreads();
  if (t == 0) {
    int c = 0;
    for (int b = 0; b < nb; ++b) { int v = l[b]; l[b] = c; c += v; }
  }
  __syncthreads();
  if (t < nb) bsum[t] = l[t];
}

__global__ void scan_final_kernel(const int* __restrict__ deg, const int* __restrict__ bsum,
                                  int* __restrict__ off, int* __restrict__ cur, int n) {
  __shared__ int l[256];
  int i = blockIdx.x * 256 + threadIdx.x;
  int t = threadIdx.x;
  int v = (i < n) ? deg[i] : 0;
  l[t] = v;
  __syncthreads();
#pragma unroll
  for (int s = 1; s < 256; s <<= 1) {
    int add = (t >= s) ? l[t - s] : 0;
    __syncthreads();
    l[t] += add;
    __syncthreads();
  }
  int incl = l[t];
  int base = bsum[blockIdx.x];
  if (i < n) {
    int e = base + incl - v;
    off[i] = e; cur[i] = e;
    if (i == n - 1) off[n] = base + incl;
  }
}

__global__ void csr_scatter_kernel(const int* __restrict__ s, const int* __restrict__ r,
                                   int* __restrict__ cur, int* __restrict__ idx, int E, int n) {
  int e = blockIdx.x * 256 + threadIdx.x;
  if (e >= E) return;
  int ss = s[e];
  if (ss >= n) return;
  int rr = r[e];
  idx[atomicAdd(&cur[rr], 1)] = ss;
  idx[atomicAdd(&cur[ss], 1)] = rr;
}

// XCD-partitioned scatter: 8 node-range groups, group = blockIdx&7 (round-robin
// block->XCD heuristic). Each group streams all edges but writes only its node
// range, so idx lines are dirtied by (mostly) one XCD's L2 and coalesce.
__global__ void csr_scatter_part_kernel(const int* __restrict__ s, const int* __restrict__ r,
                                        int* __restrict__ cur, int* __restrict__ idx,
                                        int E, int n, int rshift) {
  int g = blockIdx.x & 7;
  int nb = gridDim.x >> 3;
  int bb = blockIdx.x >> 3;
  int lo = g << rshift, hi = (g + 1) << rshift;
  int stride = nb * 256;
  for (int e = bb * 256 + threadIdx.x; e < E; e += stride) {
    int ss = s[e];
    if (ss >= n) continue;
    int rr = r[e];
    if (rr >= lo && rr < hi) idx[atomicAdd(&cur[rr], 1)] = ss;
    if (ss >= lo && ss < hi) idx[atomicAdd(&cur[ss], 1)] = rr;
  }
}

// ---- down-path f32 aggregation (C=128) ----
__global__ void agg_kernel(const float* __restrict__ x, const int* __restrict__ off,
                           const int* __restrict__ idx, float* __restrict__ agg, int n) {
  int wave = threadIdx.x >> 6, lane = threadIdx.x & 63;
  int v = blockIdx.x * 4 + wave;
  if (v >= n) return;
  int lo = off[v], hi = off[v + 1];
  int c = lane * 2;
  float ax = 0.f, ay = 0.f;
  int j = lo;
  for (; j + 4 <= hi; j += 4) {
    int u0 = idx[j], u1 = idx[j + 1], u2 = idx[j + 2], u3 = idx[j + 3];
    float2 a0 = *(const float2*)&x[(size_t)u0 * 128 + c];
    float2 a1 = *(const float2*)&x[(size_t)u1 * 128 + c];
    float2 a2 = *(const float2*)&x[(size_t)u2 * 128 + c];
    float2 a3 = *(const float2*)&x[(size_t)u3 * 128 + c];
    ax += a0.x + a1.x + a2.x + a3.x;
    ay += a0.y + a1.y + a2.y + a3.y;
  }
  for (; j < hi; ++j) {
    int u = idx[j];
    float2 a = *(const float2*)&x[(size_t)u * 128 + c];
    ax += a.x; ay += a.y;
  }
  float2 o; o.x = ax; o.y = ay;
  *(float2*)&agg[(size_t)v * 128 + c] = o;
}

// ---- up-path bf16 aggregation (C=256 bf16 in, bf16 out, f32 accum) ----
__global__ void agg_bf_kernel(const u16* __restrict__ x, const int* __restrict__ off,
                              const int* __restrict__ idx, u16* __restrict__ agg, int n) {
  int wave = threadIdx.x >> 6, lane = threadIdx.x & 63;
  int v = blockIdx.x * 4 + wave;
  if (v >= n) return;
  int lo = off[v], hi = off[v + 1];
  int c = lane * 4;
  float a0 = 0.f, a1 = 0.f, a2 = 0.f, a3 = 0.f;
  int j = lo;
  for (; j + 8 <= hi; j += 8) {
    int us[8];
#pragma unroll
    for (int q = 0; q < 8; ++q) us[q] = idx[j + q];
#pragma unroll
    for (int q = 0; q < 8; ++q) {
      ushort4 b = *(const ushort4*)&x[(size_t)us[q] * 256 + c];
      a0 += bf2f(b.x); a1 += bf2f(b.y); a2 += bf2f(b.z); a3 += bf2f(b.w);
    }
  }
  for (; j < hi; ++j) {
    ushort4 b = *(const ushort4*)&x[(size_t)idx[j] * 256 + c];
    a0 += bf2f(b.x); a1 += bf2f(b.y); a2 += bf2f(b.z); a3 += bf2f(b.w);
  }
  ushort4 o = make_ushort4(f2bf(a0), f2bf(a1), f2bf(a2), f2bf(a3));
  *(ushort4*)&agg[(size_t)v * 256 + c] = o;
}

// ---- down-path f32 GEMM (CIN=128), 32-row tile for occupancy/balance ----
template <bool GELU>
__global__ __launch_bounds__(256) void gemm_kernel(const float* __restrict__ A,
                                                   const float* __restrict__ W,
                                                   const float* __restrict__ bias,
                                                   float* __restrict__ out, int n) {
  __shared__ float As[32 * 32];
  __shared__ float Ws[32 * 128];
  int t = threadIdx.x;
  int row0 = blockIdx.x * 32;
  int colg = (t & 31) << 2;
  int rowg = (t >> 5) << 2;  // 0,4,..,28
  float acc[4][4];
#pragma unroll
  for (int i = 0; i < 4; ++i)
#pragma unroll
    for (int j = 0; j < 4; ++j) acc[i][j] = 0.f;

  for (int k0 = 0; k0 < 128; k0 += 32) {
    __syncthreads();
    {
      int ar = t >> 3, ac = (t & 7) << 2;
      float4 av = make_float4(0.f, 0.f, 0.f, 0.f);
      if (row0 + ar < n) av = *(const float4*)&A[(size_t)(row0 + ar) * 128 + k0 + ac];
      *(float4*)&As[ar * 32 + ac] = av;
    }
#pragma unroll
    for (int l = 0; l < 4; ++l) {
      int id = t + l * 256;
      int kk = id >> 5, wc = (id & 31) << 2;
      *(float4*)&Ws[kk * 128 + wc] = *(const float4*)&W[(size_t)(k0 + kk) * 128 + wc];
    }
    __syncthreads();
#pragma unroll
    for (int kk = 0; kk < 32; kk += 4) {
      float4 wv[4];
#pragma unroll
      for (int j = 0; j < 4; ++j) wv[j] = *(const float4*)&Ws[(kk + j) * 128 + colg];
#pragma unroll
      for (int i = 0; i < 4; ++i) {
        float4 av = *(const float4*)&As[(rowg + i) * 32 + kk];
        acc[i][0] += av.x * wv[0].x + av.y * wv[1].x + av.z * wv[2].x + av.w * wv[3].x;
        acc[i][1] += av.x * wv[0].y + av.y * wv[1].y + av.z * wv[2].y + av.w * wv[3].y;
        acc[i][2] += av.x * wv[0].z + av.y * wv[1].z + av.z * wv[2].z + av.w * wv[3].z;
        acc[i][3] += av.x * wv[0].w + av.y * wv[1].w + av.z * wv[2].w + av.w * wv[3].w;
      }
    }
  }
  float4 bv = *(const float4*)&bias[colg];
#pragma unroll
  for (int i = 0; i < 4; ++i) {
    int rr = row0 + rowg + i;
    if (rr < n) {
      float4 o = make_float4(acc[i][0] + bv.x, acc[i][1] + bv.y, acc[i][2] + bv.z, acc[i][3] + bv.w);
      if (GELU) { o.x = gelu_f(o.x); o.y = gelu_f(o.y); o.z = gelu_f(o.z); o.w = gelu_f(o.w); }
      *(float4*)&out[(size_t)rr * 128 + colg] = o;
    }
  }
}

// ---- up-path MFMA GEMM: out[n,128] = act(A[n,K](bf16) @ W[K,128] + bias) ----
template <int K, bool GELU, bool OUTBF>
__global__ __launch_bounds__(256) void gemm_mfma_kernel(const u16* __restrict__ A,
                                                        const u16* __restrict__ WT,
                                                        const float* __restrict__ bias,
                                                        void* __restrict__ out, int n) {
  __shared__ u16 As[64 * 72];
  __shared__ u16 Ws[128 * 72];
  int t = threadIdx.x;
  int lane = t & 63, wave = t >> 6;
  int row0 = blockIdx.x * 64;
  f32x4 acc[8];
#pragma unroll
  for (int i = 0; i < 8; ++i) acc[i] = (f32x4){0.f, 0.f, 0.f, 0.f};

  for (int k0 = 0; k0 < K; k0 += 64) {
    __syncthreads();
#pragma unroll
    for (int i = 0; i < 2; ++i) {  // A tile 64x64 bf16
      int c = t + i * 256;
      int r = c >> 3, seg = c & 7;
      bf16x8 v = {0, 0, 0, 0, 0, 0, 0, 0};
      if (row0 + r < n) v = *(const bf16x8*)&A[(size_t)(row0 + r) * K + k0 + seg * 8];
      *(bf16x8*)&As[r * 72 + seg * 8] = v;
    }
#pragma unroll
    for (int i = 0; i < 4; ++i) {  // WT tile 128x64 bf16
      int c = t + i * 256;
      int r = c >> 3, seg = c & 7;
      *(bf16x8*)&Ws[r * 72 + seg * 8] = *(const bf16x8*)&WT[(size_t)r * K + k0 + seg * 8];
    }
    __syncthreads();
#pragma unroll
    for (int kk = 0; kk < 64; kk += 32) {
      bf16x8 a = *(const bf16x8*)&As[(wave * 16 + (lane & 15)) * 72 + kk + (lane >> 4) * 8];
#pragma unroll
      for (int ct = 0; ct < 8; ++ct) {
        bf16x8 b = *(const bf16x8*)&Ws[(ct * 16 + (lane & 15)) * 72 + kk + (lane >> 4) * 8];
        acc[ct] = __builtin_amdgcn_mfma_f32_16x16x32_bf16(a, b, acc[ct], 0, 0, 0);
      }
    }
  }
  int colb = lane & 15, rquad = lane >> 4;
#pragma unroll
  for (int ct = 0; ct < 8; ++ct) {
#pragma unroll
    for (int r = 0; r < 4; ++r) {
      int row = row0 + wave * 16 + rquad * 4 + r;
      if (row < n) {
        int col = ct * 16 + colb;
        float v = acc[ct][r] + bias[col];
        if (GELU) v = gelu_f(v);
        if (OUTBF) ((u16*)out)[(size_t)row * 128 + col] = f2bf(v);
        else       ((float*)out)[(size_t)row * 128 + col] = v;
      }
    }
  }
}

// fused convert+transpose of all 9 up-path weights, one dispatch
__global__ void wconv_all_kernel(const float* __restrict__ uW1, const float* __restrict__ uW2,
                                 const float* __restrict__ uW3, u16* __restrict__ wt1,
                                 u16* __restrict__ wt2, u16* __restrict__ wt3) {
  int i = blockIdx.x * 256 + threadIdx.x;
  if (i >= 3 * 65536) return;
  int lvl = i >> 16, rem = i & 65535;
  if (rem < 32768) {  // W1: [256][128] -> [128][256]
    int k = rem >> 7, c = rem & 127;
    wt1[(size_t)lvl * 32768 + c * 256 + k] = f2bf(uW1[(size_t)lvl * 32768 + rem]);
  } else if (rem < 49152) {
    int j = rem - 32768; int k = j >> 7, c = j & 127;
    wt2[(size_t)lvl * 16384 + c * 128 + k] = f2bf(uW2[(size_t)lvl * 16384 + j]);
  } else {
    int j = rem - 49152; int k = j >> 7, c = j & 127;
    wt3[(size_t)lvl * 16384 + c * 128 + k] = f2bf(uW3[(size_t)lvl * 16384 + j]);
  }
}

__global__ void ln_kernel(const float* __restrict__ h, const float* __restrict__ g,
                          const float* __restrict__ beta, float* __restrict__ out, int n) {
  int wave = threadIdx.x >> 6, lane = threadIdx.x & 63;
  int i = blockIdx.x * 4 + wave;
  if (i >= n) return;
  float2 hv = *(const float2*)&h[(size_t)i * 128 + lane * 2];
  float s = hv.x + hv.y;
  for (int o = 32; o; o >>= 1) s += __shfl_down(s, o, 64);
  float mu = __shfl(s, 0, 64) * (1.0f / 128.0f);
  float dx = hv.x - mu, dy = hv.y - mu;
  float q = dx * dx + dy * dy;
  for (int o = 32; o; o >>= 1) q += __shfl_down(q, o, 64);
  float var = __shfl(q, 0, 64) * (1.0f / 128.0f);
  float rs = rsqrtf(var + 1e-5f);
  float2 gv = *(const float2*)&g[lane * 2];
  float2 bv = *(const float2*)&beta[lane * 2];
  float2 o2; o2.x = gv.x * dx * rs + bv.x; o2.y = gv.y * dy * rs + bv.y;
  *(float2*)&out[(size_t)i * 128 + lane * 2] = o2;
}

// cat (bf16): [:, :128] = res ; [:, 128:] = 0
__global__ void cat_res_bf_kernel(const float* __restrict__ res, u16* __restrict__ cat, int n) {
  int gid = blockIdx.x * 256 + threadIdx.x;
  int row = gid >> 6;
  if (row >= n) return;
  int q = gid & 63;
  int c = q << 2;
  if (q < 32) {
    float4 a = *(const float4*)&res[(size_t)row * 128 + c];
    *(ushort4*)&cat[(size_t)row * 256 + c] = make_ushort4(f2bf(a.x), f2bf(a.y), f2bf(a.z), f2bf(a.w));
  } else {
    *(ushort4*)&cat[(size_t)row * 256 + c] = make_ushort4(0, 0, 0, 0);
  }
}

// cat[perm[t], 128:] = xdeep[t, :]
__global__ void cat_up_bf_kernel(const float* __restrict__ xd, const int* __restrict__ perm,
                                 u16* __restrict__ cat, int k) {
  int gid = blockIdx.x * 256 + threadIdx.x;
  int t = gid >> 5;
  if (t >= k) return;
  int c = (gid & 31) << 2;
  float4 a = *(const float4*)&xd[(size_t)t * 128 + c];
  *(ushort4*)&cat[(size_t)perm[t] * 256 + 128 + c] =
      make_ushort4(f2bf(a.x), f2bf(a.y), f2bf(a.z), f2bf(a.w));
}

// ---------------------------------------------------------------------------

static inline int cdiv(int a, int b) { return (a + b - 1) / b; }

extern "C" void kernel_launch(void* const* d_in, const int* in_sizes, int n_in,
                              void* d_out, int out_size, void* d_ws, size_t ws_size,
                              hipStream_t stream) {
  const float* x0   = (const float*)d_in[0];
  const int*   snd  = (const int*)d_in[1];
  const int*   rcv  = (const int*)d_in[2];
  const float* poolw = (const float*)d_in[3];
  const float* dW1 = (const float*)d_in[4];
  const float* db1 = (const float*)d_in[5];
  const float* dW2 = (const float*)d_in[6];
  const float* db2 = (const float*)d_in[7];
  const float* dW3 = (const float*)d_in[8];
  const float* db3 = (const float*)d_in[9];
  const float* dg  = (const float*)d_in[10];
  const float* dbe = (const float*)d_in[11];
  const float* uW1 = (const float*)d_in[12];
  const float* ub1 = (const float*)d_in[13];
  const float* uW2 = (const float*)d_in[14];
  const float* ub2 = (const float*)d_in[15];
  const float* uW3 = (const float*)d_in[16];
  const float* ub3 = (const float*)d_in[17];
  const float* ug  = (const float*)d_in[18];
  const float* ube = (const float*)d_in[19];

  const int N0 = in_sizes[0] / 128;
  const int E  = in_sizes[1];
  const int N1 = (N0 + 1) / 2, N2 = (N1 + 1) / 2, N3 = (N2 + 1) / 2;

  // ---- workspace carve ----
  char* p = (char*)d_ws;
  auto alloc = [&](size_t bytes) -> void* {
    void* r = (void*)p;
    p += (bytes + 255) & ~(size_t)255;
    return r;
  };
  float* key  = (float*)alloc((size_t)N0 * 4);
  float* valt = (float*)alloc((size_t)N0 * 4);
  int*   hist = (int*)alloc((size_t)2 * 65536 * 4);  // hi | lo halves
  int*   csum = (int*)alloc(256 * 4);
  int*   meta = (int*)alloc(64 * 4);
  int*   tcnt = (int*)alloc(512 * 4);
  int*   toff = (int*)alloc(512 * 4);
  int*   bsum = (int*)alloc(256 * 4);
  unsigned char* selt = (unsigned char*)alloc((size_t)N0);
  int*   nmap = (int*)alloc((size_t)(N0 + 1) * 4);
  int*   perm0 = (int*)alloc((size_t)N1 * 4);
  int*   perm1 = (int*)alloc((size_t)N2 * 4);
  int*   perm2 = (int*)alloc((size_t)N3 * 4);
  float* vals  = (float*)alloc((size_t)N1 * 4);
  // edge lists (down only; h2b aliases this region during up)
  int* s1 = (int*)alloc((size_t)E * 4); int* r1 = (int*)alloc((size_t)E * 4);
  int* s2 = (int*)alloc((size_t)E * 4); int* r2 = (int*)alloc((size_t)E * 4);
  int* s3 = (int*)alloc((size_t)E * 4); int* r3 = (int*)alloc((size_t)E * 4);
  float* x1 = (float*)alloc((size_t)N1 * 128 * 4);
  float* x2 = (float*)alloc((size_t)N2 * 128 * 4);
  float* x3 = (float*)alloc((size_t)N3 * 128 * 4);
  float* xp = (float*)alloc((size_t)N1 * 128 * 4);   // down only; h1b aliases
  float* xu2 = (float*)alloc((size_t)N2 * 128 * 4);
  float* xu1 = (float*)alloc((size_t)N1 * 128 * 4);
  float* aggf = (float*)alloc((size_t)N1 * 128 * 4); // down agg out
  float* h1f  = (float*)alloc((size_t)N1 * 128 * 4); // down mlp scratch
  float* h2f  = (float*)alloc((size_t)N1 * 128 * 4);
  u16* agg_bf = (u16*)alloc((size_t)N0 * 256 * 2);   // up agg out
  u16* cat_bf = (u16*)alloc((size_t)N0 * 256 * 2);   // up cat; reused as f32 GEMM3 out
  u16* wt1 = (u16*)alloc((size_t)3 * 128 * 256 * 2);
  u16* wt2 = (u16*)alloc((size_t)3 * 128 * 128 * 2);
  u16* wt3 = (u16*)alloc((size_t)3 * 128 * 128 * 2);
  int* off0 = (int*)alloc((size_t)(N0 + 1) * 4); int* cur0 = (int*)alloc((size_t)N0 * 4);
  int* idx0 = (int*)alloc((size_t)2 * E * 4);
  int* off1 = (int*)alloc((size_t)(N1 + 1) * 4); int* cur1 = (int*)alloc((size_t)N1 * 4);
  int* idx1 = (int*)alloc((size_t)2 * E * 4);
  int* off2 = (int*)alloc((size_t)(N2 + 1) * 4); int* cur2 = (int*)alloc((size_t)N2 * 4);
  int* idx2 = (int*)alloc((size_t)2 * E * 4);
  int* off3 = (int*)alloc((size_t)(N3 + 1) * 4); int* cur3 = (int*)alloc((size_t)N3 * 4);
  int* idx3 = (int*)alloc((size_t)2 * E * 4);

  // phase-disjoint aliases (up-phase bf16 activations over dead down buffers)
  u16* h1b = (u16*)xp;              // N0*128*2 over xp
  u16* h2b = (u16*)s1;              // N0*128*2 over s1..r3
  float* hfin = (float*)cat_bf;     // N0*128*4 over cat_bf

  auto run_scan = [&](int* curB, int* offB, int n) {
    int nb = cdiv(n, 256);
    scan_part_kernel<<<nb, 256, 0, stream>>>(curB, bsum, n);
    scan_bsum_kernel<<<1, 256, 0, stream>>>(bsum, nb);
    scan_final_kernel<<<nb, 256, 0, stream>>>(curB, bsum, offB, curB, n);
  };

  auto run_scatter = [&](const int* s, const int* r, int* cur, int* idx, int n) {
    if (n >= 16384) {
      int nb = cdiv(E, 2048);
      int per = cdiv(n, 8);
      int rshift = 0;
      while ((1 << rshift) < per) ++rshift;
      csr_scatter_part_kernel<<<nb * 8, 256, 0, stream>>>(s, r, cur, idx, E, n, rshift);
    } else {
      csr_scatter_kernel<<<cdiv(E, 256), 256, 0, stream>>>(s, r, cur, idx, E, n);
    }
  };

  // ---- weight convert/transpose (bf16, up path only; one dispatch) ----
  wconv_all_kernel<<<cdiv(3 * 65536, 256), 256, 0, stream>>>(uW1, uW2, uW3, wt1, wt2, wt3);

  // ---- level-0 CSR (for the final up step) ----
  hipMemsetAsync(cur0, 0, (size_t)N0 * 4, stream);
  deg_kernel<<<cdiv(E, 256), 256, 0, stream>>>(snd, rcv, cur0, E, N0);
  run_scan(cur0, off0, N0);
  run_scatter(snd, rcv, cur0, idx0, N0);

  // ---- generic down step (f32 exact; feeds top-k selection) ----
  auto down_step = [&](int n, int k, const float* xcur, const int* sin, const int* rin,
                       int* sout, int* rout, int* permL, float* xnext, int lvl,
                       int* offL, int* curL, int* idxL) {
    int nb = cdiv(n, 256);
    score_kernel<<<cdiv(n, 4), 256, 0, stream>>>(xcur, poolw + (size_t)lvl * 128, key, valt, n);
    hipMemsetAsync(hist, 0, (size_t)2 * 65536 * 4, stream);
    hist_hi_kernel<<<nb, 256, 0, stream>>>(key, hist, n);
    chunk_sum_kernel<<<256, 256, 0, stream>>>(hist, csum);
    find_hi2_kernel<<<1, 256, 0, stream>>>(hist, csum, meta, k);
    hist_lo_kernel<<<nb, 256, 0, stream>>>(key, meta, hist + 65536, n);
    chunk_sum_kernel<<<256, 256, 0, stream>>>(hist + 65536, csum);
    find_lo2_kernel<<<1, 256, 0, stream>>>(hist + 65536, csum, meta);
    tie_count_kernel<<<nb, 256, 0, stream>>>(key, meta, tcnt, n);
    tie_scan_kernel<<<1, 256, 0, stream>>>(tcnt, toff, nb);
    tie_mark_kernel<<<nb, 256, 0, stream>>>(key, meta, toff, selt, n);
    select_kernel<<<cdiv(n + 1, 256), 256, 0, stream>>>(key, valt, selt, meta, permL, vals, nmap, n, k);
    pool_kernel<<<cdiv(k * 32, 256), 256, 0, stream>>>(xcur, permL, vals, xp, k);
    hipMemsetAsync(curL, 0, (size_t)k * 4, stream);
    remap_deg_kernel<<<cdiv(E, 256), 256, 0, stream>>>(sin, rin, nmap, sout, rout, curL, E, k);
    run_scan(curL, offL, k);
    run_scatter(sout, rout, curL, idxL, k);
    agg_kernel<<<cdiv(k, 4), 256, 0, stream>>>(xp, offL, idxL, aggf, k);
    gemm_kernel<true><<<cdiv(k, 32), 256, 0, stream>>>(
        aggf, dW1 + (size_t)lvl * 128 * 128, db1 + (size_t)lvl * 128, h1f, k);
    gemm_kernel<true><<<cdiv(k, 32), 256, 0, stream>>>(
        h1f, dW2 + (size_t)lvl * 128 * 128, db2 + (size_t)lvl * 128, h2f, k);
    gemm_kernel<false><<<cdiv(k, 32), 256, 0, stream>>>(
        h2f, dW3 + (size_t)lvl * 128 * 128, db3 + (size_t)lvl * 128, h1f, k);
    ln_kernel<<<cdiv(k, 4), 256, 0, stream>>>(h1f, dg + (size_t)lvl * 128, dbe + (size_t)lvl * 128,
                                              xnext, k);
  };

  down_step(N0, N1, x0, snd, rcv, s1, r1, perm0, x1, 0, off1, cur1, idx1);
  down_step(N1, N2, x1, s1, r1, s2, r2, perm1, x2, 1, off2, cur2, idx2);
  down_step(N2, N3, x2, s2, r2, s3, r3, perm2, x3, 2, off3, cur3, idx3);

  // ---- generic up step (bf16 path) ----
  auto up_step = [&](int n, const float* res, const int* permL, const float* xdeep, int kdeep,
                     int lvl, const int* offL, const int* idxL, float* outbuf) {
    cat_res_bf_kernel<<<cdiv(n * 64, 256), 256, 0, stream>>>(res, cat_bf, n);
    cat_up_bf_kernel<<<cdiv(kdeep * 32, 256), 256, 0, stream>>>(xdeep, permL, cat_bf, kdeep);
    agg_bf_kernel<<<cdiv(n, 4), 256, 0, stream>>>(cat_bf, offL, idxL, agg_bf, n);
    gemm_mfma_kernel<256, true, true><<<cdiv(n, 64), 256, 0, stream>>>(
        agg_bf, wt1 + (size_t)lvl * 128 * 256, ub1 + (size_t)lvl * 128, h1b, n);
    gemm_mfma_kernel<128, true, true><<<cdiv(n, 64), 256, 0, stream>>>(
        h1b, wt2 + (size_t)lvl * 128 * 128, ub2 + (size_t)lvl * 128, h2b, n);
    gemm_mfma_kernel<128, false, false><<<cdiv(n, 64), 256, 0, stream>>>(
        h2b, wt3 + (size_t)lvl * 128 * 128, ub3 + (size_t)lvl * 128, hfin, n);
    ln_kernel<<<cdiv(n, 4), 256, 0, stream>>>(hfin, ug + (size_t)lvl * 128, ube + (size_t)lvl * 128,
                                              outbuf, n);
  };

  up_step(N2, x2, perm2, x3, N3, 0, off2, idx2, xu2);
  up_step(N1, x1, perm1, xu2, N2, 1, off1, idx1, xu1);
  up_step(N0, x0, perm0, xu1, N1, 2, off0, idx0, (float*)d_out);

  (void)n_in; (void)out_size; (void)ws_size;
}